// Round 12
// baseline (714.195 us; speedup 1.0000x reference)
//
#include <hip/hip_runtime.h>
#include <hip/hip_bf16.h>

// WordSentAtt: qf = relu(Q@W^T + b); S = qf@K^T (masked); attn = softmax; O = attn@K
// B=32, Lq=Lk=D=1024, f32 in/out. Split-bf16 (hi/lo) MFMA for qf and S.
// R12: (1) k_sgemm8 -> BK=32 double-buffer: LDS 64KB -> 2 blocks/CU (m114
//   cross-block overlap; sgemm8 was the only GEMM stuck at 1 block/CU and the
//   only one below qf2). Swizzle adapted to 4 16B-slots (slot = g ^ (row&3)),
//   source pre-swizzled (rule 21). R9's issue order kept (A-loads then stage:
//   stage youngest -> A-waits leave it in flight).
//   (2) cvt_k + cvt_qw merged into one launch (k_cvt_all).

typedef __attribute__((ext_vector_type(4))) float f32x4;
typedef __attribute__((ext_vector_type(8))) short s16x8;
typedef __attribute__((ext_vector_type(4))) short s16x4;

#define MFMA16(a, b, c) __builtin_amdgcn_mfma_f32_16x16x32_bf16((a), (b), (c), 0, 0, 0)

__device__ __forceinline__ unsigned short f2bf(float x) {
  unsigned u = __builtin_bit_cast(unsigned, x);
  return (unsigned short)((u + 0x7FFFu + ((u >> 16) & 1u)) >> 16);
}
__device__ __forceinline__ float bf2f(unsigned short h) {
  return __builtin_bit_cast(float, ((unsigned)h) << 16);
}
__device__ __forceinline__ int swz(int row, int col) {
  return (row * 64 + col) ^ ((row & 7) << 3);
}
__device__ __forceinline__ void cvt8(const float* __restrict__ s, s16x8& h8, s16x8& l8) {
  f32x4 a = *(const f32x4*)s;
  f32x4 b = *(const f32x4*)(s + 4);
#pragma unroll
  for (int i = 0; i < 8; i++) {
    float v = (i < 4) ? a[i] : b[i - 4];
    unsigned short hu = f2bf(v);
    unsigned short lu = f2bf(v - bf2f(hu));
    h8[i] = (short)hu;
    l8[i] = (short)lu;
  }
}
__device__ __forceinline__ void gld16(const void* g, void* lds) {
  __builtin_amdgcn_global_load_lds((const __attribute__((address_space(1))) unsigned int*)g,
                                   (__attribute__((address_space(3))) unsigned int*)lds, 16, 0, 0);
}

// ws layout (bytes)
#define OFF_KHI 0ULL
#define OFF_KLO 67108864ULL   // dead after sgemm8 -> P bf16
#define OFF_KHIT 134217728ULL
#define OFF_QHI 201326592ULL  // Qhi; Q planes dead after qf2 -> S f32 (128MB)
#define OFF_QLO 268435456ULL  // Qlo
#define OFF_WHI 335544320ULL
#define OFF_WLO 337641472ULL
#define WS_TIER_A 339738624ULL
#define QA_LO 33554432ULL  // u16 offset of lo plane inside d_out frag layout

// ================= merged pre-convert kernel =================
// blocks [0,8192): K -> Khi/Klo/KhiT (16x16x32 tiling); [8192,25088): Q/W planes.
__global__ __launch_bounds__(256) void k_cvt_all(const float* __restrict__ K,
                                                 unsigned short* __restrict__ Khi,
                                                 unsigned short* __restrict__ Klo,
                                                 unsigned short* __restrict__ KhiT,
                                                 const float* __restrict__ Q,
                                                 unsigned short* __restrict__ Qhi,
                                                 unsigned short* __restrict__ Qlo,
                                                 const float* __restrict__ W,
                                                 unsigned short* __restrict__ Whi,
                                                 unsigned short* __restrict__ Wlo) {
  __shared__ unsigned T[64 * 65];
  const int bid = blockIdx.x;
  const int t = threadIdx.x;
  if (bid < 8192) {
    const int db0 = (bid & 15) * 64, kb0 = ((bid >> 4) & 15) * 64, b = bid >> 8;
    const size_t base = (size_t)b * 1024 * 1024;
#pragma unroll
    for (int i = 0; i < 2; i++) {
      const int r = (t >> 3) + i * 32, c0 = (t & 7) * 8;
      s16x8 h, l;
      cvt8(K + base + (size_t)(kb0 + r) * 1024 + db0 + c0, h, l);
      *(s16x8*)(Khi + base + (size_t)(kb0 + r) * 1024 + db0 + c0) = h;
      *(s16x8*)(Klo + base + (size_t)(kb0 + r) * 1024 + db0 + c0) = l;
#pragma unroll
      for (int j = 0; j < 8; j++)
        T[r * 65 + c0 + j] = ((unsigned)(unsigned short)h[j] << 16) | (unsigned short)l[j];
    }
    __syncthreads();
#pragma unroll
    for (int i = 0; i < 2; i++) {
      const int rd = (t >> 3) + i * 32, ck0 = (t & 7) * 8;
      s16x8 h;
#pragma unroll
      for (int j = 0; j < 8; j++) h[j] = (short)(unsigned short)(T[(ck0 + j) * 65 + rd] >> 16);
      *(s16x8*)(KhiT + base + (size_t)(db0 + rd) * 1024 + kb0 + ck0) = h;
    }
  } else {
    const int i = (bid - 8192) * 256 + t;
    s16x8 h, l;
    if (i < 4194304) {
      cvt8(Q + (size_t)i * 8, h, l);
      *(s16x8*)(Qhi + (size_t)i * 8) = h;
      *(s16x8*)(Qlo + (size_t)i * 8) = l;
    } else {
      int j = i - 4194304;
      if (j < 131072) {
        cvt8(W + (size_t)j * 8, h, l);
        *(s16x8*)(Whi + (size_t)j * 8) = h;
        *(s16x8*)(Wlo + (size_t)j * 8) = l;
      }
    }
  }
}

// ================= qf GEMM -> fragment-ordered output (R9/R11 version) ========
__global__ __launch_bounds__(256, 2) void k_qf2(const unsigned short* __restrict__ Qhi,
                                                const unsigned short* __restrict__ Qlo,
                                                const unsigned short* __restrict__ Whi,
                                                const unsigned short* __restrict__ Wlo,
                                                const float* __restrict__ bias,
                                                float* __restrict__ outp) {
  __shared__ __align__(16) unsigned short Ah[128 * 64], Al[128 * 64], Bh[128 * 64], Bl[128 * 64];
  const int t = threadIdx.x;
  const int i = blockIdx.x + blockIdx.y * 256;
  const int x = i & 7, j = i >> 3;
  const int n0 = (j & 7) * 128;
  const int m0 = (x * 32 + (j >> 3)) * 128;
  const int w = t >> 6, l = t & 63, wm = w >> 1, wn = w & 1, g = l >> 4, ln = l & 15;
  const int lrow = l >> 3, lc8 = (l & 7) * 8;
  const f32x4 fz = {0.f, 0.f, 0.f, 0.f};
  f32x4 acc[4][4];
#pragma unroll
  for (int a = 0; a < 4; a++)
#pragma unroll
    for (int bq = 0; bq < 4; bq++) acc[a][bq] = fz;
#pragma unroll 1
  for (int k0 = 0; k0 < 1024; k0 += 64) {
#pragma unroll
    for (int jj = 0; jj < 4; jj++) {
      const int ch = w * 4 + jj;
      const int row = ch * 8 + lrow;
      const int sc = lc8 ^ (lrow << 3);
      gld16(Qhi + (size_t)(m0 + row) * 1024 + k0 + sc, &Ah[ch * 512]);
      gld16(Qlo + (size_t)(m0 + row) * 1024 + k0 + sc, &Al[ch * 512]);
      gld16(Whi + (size_t)(n0 + row) * 1024 + k0 + sc, &Bh[ch * 512]);
      gld16(Wlo + (size_t)(n0 + row) * 1024 + k0 + sc, &Bl[ch * 512]);
    }
    __syncthreads();
#pragma unroll
    for (int ks = 0; ks < 2; ks++) {
      const int kc = ks * 32 + g * 8;
      s16x8 ah[4], al[4], bh[4], bl[4];
#pragma unroll
      for (int mf = 0; mf < 4; mf++) {
        const int row = wm * 64 + mf * 16 + ln;
        const int idx = row * 64 + (kc ^ ((row & 7) << 3));
        ah[mf] = *(const s16x8*)&Ah[idx];
        al[mf] = *(const s16x8*)&Al[idx];
      }
#pragma unroll
      for (int nf = 0; nf < 4; nf++) {
        const int row = wn * 64 + nf * 16 + ln;
        const int idx = row * 64 + (kc ^ ((row & 7) << 3));
        bh[nf] = *(const s16x8*)&Bh[idx];
        bl[nf] = *(const s16x8*)&Bl[idx];
      }
#pragma unroll
      for (int mf = 0; mf < 4; mf++)
#pragma unroll
        for (int nf = 0; nf < 4; nf++) {
          acc[mf][nf] = MFMA16(ah[mf], bh[nf], acc[mf][nf]);
          acc[mf][nf] = MFMA16(ah[mf], bl[nf], acc[mf][nf]);
          acc[mf][nf] = MFMA16(al[mf], bh[nf], acc[mf][nf]);
        }
    }
    __syncthreads();
  }
  unsigned short* qA = (unsigned short*)outp;
#pragma unroll
  for (int nf = 0; nf < 4; nf++) {
    const int c = n0 + wn * 64 + nf * 16 + ln;
    const float bv = bias[c];
    const int kchunk = c >> 5, lhib = ((c >> 3) & 3) << 4, jj = c & 7;
#pragma unroll
    for (int mf = 0; mf < 4; mf++)
#pragma unroll
      for (int r = 0; r < 4; r++) {
        const int R = m0 + wm * 64 + mf * 16 + g * 4 + r;
        float v = acc[mf][nf][r] + bv;
        v = v > 0.f ? v : 0.f;
        unsigned short h = f2bf(v);
        const size_t fo = (((size_t)(R >> 4) * 32 + kchunk) * 64 + ((R & 15) + lhib)) * 8 + jj;
        qA[fo] = h;
        qA[QA_LO + fo] = f2bf(v - bf2f(h));
      }
  }
}

// ================= S = qf @ K^T, 256x256, BK=32 dbuf, 2 blocks/CU (R12) =======
__global__ __launch_bounds__(512, 2) void k_sgemm8(const unsigned short* __restrict__ Khi,
                                                   const unsigned short* __restrict__ Klo,
                                                   const unsigned short* __restrict__ qA,
                                                   float* __restrict__ Sf) {
  __shared__ __align__(16) unsigned short Bh[2][256 * 32], Bl[2][256 * 32];  // 64KB
  const int t = threadIdx.x;
  const int i = blockIdx.x;
  const int x = i & 7, jj = i >> 3;
  const int b = x * 4 + (jj >> 4);
  const int qt = (jj >> 2) & 3, nt = jj & 3;
  const int q0g = b * 1024 + qt * 256;
  const int k0g = nt * 256;
  const int w = t >> 6, l = t & 63, wm = w >> 2, wn = w & 3, g = l >> 4, ln = l & 15;
  const size_t kbase = (size_t)b * 1024 * 1024;
  const int qb0 = (q0g >> 4) + wm * 8;
  // stage geometry: chunk ch covers rows [ch*16, ch*16+16); lane l -> row
  // ch*16 + (l>>2), src 16B-slot (l&3)^((l>>2)&3) (pre-swizzle, rule 21)
  const int srow_in = l >> 2;                      // 0..15 within chunk
  const int sslot = (l & 3) ^ (srow_in & 3);       // swizzled source slot
  const f32x4 fz = {0.f, 0.f, 0.f, 0.f};
  f32x4 acc[8][4];
#pragma unroll
  for (int a = 0; a < 8; a++)
#pragma unroll
    for (int bq = 0; bq < 4; bq++) acc[a][bq] = fz;

  auto stageB = [&](int buf, int dc) {
#pragma unroll
    for (int jj2 = 0; jj2 < 2; jj2++) {
      const int ch = w * 2 + jj2;         // 0..15
      const int row = ch * 16 + srow_in;  // 0..255
      const size_t go = kbase + (size_t)(k0g + row) * 1024 + dc * 32 + sslot * 8;
      gld16(Khi + go, &Bh[buf][ch * 512]);
      gld16(Klo + go, &Bl[buf][ch * 512]);
    }
  };

  stageB(0, 0);
#pragma unroll 1
  for (int dc = 0; dc < 32; dc++) {
    const int cur = dc & 1;
    asm volatile("s_waitcnt vmcnt(0)" ::: "memory");
    __builtin_amdgcn_s_barrier();
    __builtin_amdgcn_sched_barrier(0);
    // A-frags first, stage after (stage youngest -> A-wait leaves it in flight)
    s16x8 ah[8], al[8];
#pragma unroll
    for (int mf = 0; mf < 8; mf++) {
      const size_t fo = (((size_t)(qb0 + mf) * 32 + dc) * 64 + l) * 8;
      ah[mf] = *(const s16x8*)(qA + fo);
      al[mf] = *(const s16x8*)(qA + QA_LO + fo);
    }
    __builtin_amdgcn_sched_barrier(0);
    if (dc < 31) stageB(cur ^ 1, dc + 1);
    __builtin_amdgcn_sched_barrier(0);
    s16x8 bh[4], bl[4];
#pragma unroll
    for (int nf = 0; nf < 4; nf++) {
      const int row = wn * 64 + nf * 16 + ln;
      const int idx = row * 32 + ((g ^ (row & 3)) * 8);
      bh[nf] = *(const s16x8*)&Bh[cur][idx];
      bl[nf] = *(const s16x8*)&Bl[cur][idx];
    }
    __builtin_amdgcn_s_setprio(1);
#pragma unroll
    for (int mf = 0; mf < 8; mf++)
#pragma unroll
      for (int nf = 0; nf < 4; nf++) {
        acc[mf][nf] = MFMA16(ah[mf], bh[nf], acc[mf][nf]);
        acc[mf][nf] = MFMA16(ah[mf], bl[nf], acc[mf][nf]);
        acc[mf][nf] = MFMA16(al[mf], bh[nf], acc[mf][nf]);
      }
    __builtin_amdgcn_s_setprio(0);
  }
  // epilogue: S as f32 (single plane)
#pragma unroll
  for (int mf = 0; mf < 8; mf++)
#pragma unroll
    for (int nf = 0; nf < 4; nf++) {
      const int colS = k0g + wn * 64 + nf * 16 + ln;
#pragma unroll
      for (int r = 0; r < 4; r++) {
        const int rowS = q0g + wm * 128 + mf * 16 + g * 4 + r;
        Sf[(size_t)rowS * 1024 + colS] = acc[mf][nf][r];
      }
    }
}

// ================= masked softmax, streaming (f32 input) ======================
__global__ __launch_bounds__(256) void k_softmax(const float* __restrict__ Sf,
                                                 const float* __restrict__ mask,
                                                 unsigned short* __restrict__ P) {
  __shared__ float red[2][4];
  const int row = blockIdx.x;
  const int b = row >> 10;
  const int t = threadIdx.x, w = t >> 6, l = t & 63;
  const size_t base = (size_t)row * 1024 + t * 4;
  const f32x4 sv = *(const f32x4*)(Sf + base);
  const f32x4 mk = *(const f32x4*)(mask + b * 1024 + t * 4);
  float s[4];
  bool um[4];
#pragma unroll
  for (int j = 0; j < 4; j++) {
    s[j] = sv[j];
    um[j] = mk[j] != 0.f;
  }
  float mx = -1e30f;
#pragma unroll
  for (int j = 0; j < 4; j++)
    if (um[j]) mx = fmaxf(mx, s[j]);
#pragma unroll
  for (int off = 1; off < 64; off <<= 1) mx = fmaxf(mx, __shfl_xor(mx, off));
  if (l == 0) red[0][w] = mx;
  __syncthreads();
  mx = fmaxf(fmaxf(red[0][0], red[0][1]), fmaxf(red[0][2], red[0][3]));
  float e[4];
  float sum = 0.f;
#pragma unroll
  for (int j = 0; j < 4; j++) {
    e[j] = um[j] ? __expf(s[j] - mx) : 0.f;
    sum += e[j];
  }
#pragma unroll
  for (int off = 1; off < 64; off <<= 1) sum += __shfl_xor(sum, off);
  if (l == 0) red[1][w] = sum;
  __syncthreads();
  const float rinv = 1.f / (red[1][0] + red[1][1] + red[1][2] + red[1][3]);
  s16x4 o;
#pragma unroll
  for (int j = 0; j < 4; j++) o[j] = (short)f2bf(e[j] * rinv);
  *(s16x4*)(P + base) = o;
}

// ================= O = attn @ K via KhiT (unchanged) ==========================
__global__ __launch_bounds__(512, 1) void k_pv2(const unsigned short* __restrict__ KhiT,
                                                const unsigned short* __restrict__ attnw,
                                                float* __restrict__ dout) {
  __shared__ __align__(16) unsigned short Pb[2][128 * 64];
  __shared__ __align__(16) unsigned short KTb[2][512 * 64];
  const int t = threadIdx.x;
  const int i = blockIdx.y * 8 + blockIdx.x;
  const int x = i & 7, jj = i >> 3;
  const int b = x * 4 + (jj >> 3), qt = jj & 7;
  const int q0 = qt * 128, d0 = blockIdx.z * 512;
  const int w = t >> 6, l = t & 63, wm = w >> 2, wd = w & 3, g = l >> 4, ln = l & 15;
  const int lrow = l >> 3, lc8 = (l & 7) * 8, sc = lc8 ^ (lrow << 3);
  const f32x4 fz = {0.f, 0.f, 0.f, 0.f};
  f32x4 acc[4][8];
#pragma unroll
  for (int a = 0; a < 4; a++)
#pragma unroll
    for (int bq = 0; bq < 8; bq++) acc[a][bq] = fz;
  const size_t kbase = (size_t)b * 1024 * 1024;

  auto stageP = [&](int buf, int k0) {
#pragma unroll
    for (int jj2 = 0; jj2 < 2; jj2++) {
      const int ch = w * 2 + jj2;
      const int row = ch * 8 + lrow;
      gld16(attnw + (size_t)(b * 1024 + q0 + row) * 1024 + k0 + sc, &Pb[buf][ch * 512]);
    }
  };
  auto stageKT = [&](int buf, int k0) {
#pragma unroll
    for (int jj2 = 0; jj2 < 8; jj2++) {
      const int ch = w * 8 + jj2;
      const int row = ch * 8 + lrow;
      gld16(KhiT + kbase + (size_t)(d0 + row) * 1024 + k0 + sc, &KTb[buf][ch * 512]);
    }
  };

  stageP(0, 0);
  stageKT(0, 0);
#pragma unroll 1
  for (int s = 0; s < 16; s++) {
    asm volatile("s_waitcnt vmcnt(0)" ::: "memory");
    __builtin_amdgcn_s_barrier();
    __builtin_amdgcn_sched_barrier(0);
    if (s < 15) {
      stageP((s + 1) & 1, (s + 1) * 64);
      stageKT((s + 1) & 1, (s + 1) * 64);
    }
    const int cur = s & 1;
    __builtin_amdgcn_s_setprio(1);
#pragma unroll
    for (int ks = 0; ks < 2; ks++) {
      const int kc = ks * 32 + g * 8;
      s16x8 a[4], bb[8];
#pragma unroll
      for (int mf = 0; mf < 4; mf++) {
        const int row = wm * 64 + mf * 16 + ln;
        a[mf] = *(const s16x8*)&Pb[cur][row * 64 + (kc ^ ((row & 7) << 3))];
      }
#pragma unroll
      for (int nf = 0; nf < 8; nf++) {
        const int row = wd * 128 + nf * 16 + ln;
        bb[nf] = *(const s16x8*)&KTb[cur][row * 64 + (kc ^ ((row & 7) << 3))];
      }
#pragma unroll
      for (int mf = 0; mf < 4; mf++)
#pragma unroll
        for (int nf = 0; nf < 8; nf++) acc[mf][nf] = MFMA16(a[mf], bb[nf], acc[mf][nf]);
    }
    __builtin_amdgcn_s_setprio(0);
  }
#pragma unroll
  for (int mf = 0; mf < 4; mf++)
#pragma unroll
    for (int nf = 0; nf < 8; nf++)
#pragma unroll
      for (int r = 0; r < 4; r++) {
        const int q = q0 + wm * 64 + mf * 16 + g * 4 + r;
        const int d = d0 + wd * 128 + nf * 16 + ln;
        dout[(size_t)(b * 1024 + q) * 1024 + d] = acc[mf][nf][r];
      }
}

// ================= Tier C: round-1 kernels (fallback, unchanged) =============
__global__ __launch_bounds__(256, 2) void k_qf(const float* __restrict__ Q,
                                               const float* __restrict__ W,
                                               const float* __restrict__ bias,
                                               float* __restrict__ qf) {
  __shared__ __align__(16) short Ah[128 * 64], Al[128 * 64], Bh[128 * 64], Bl[128 * 64];
  const int t = threadIdx.x;
  const int m0 = blockIdx.x * 128, n0 = blockIdx.y * 128;
  const int w = t >> 6, l = t & 63, wm = w >> 1, wn = w & 1, g = l >> 4, ln = l & 15;
  const f32x4 fz = {0.f, 0.f, 0.f, 0.f};
  f32x4 acc[4][4];
#pragma unroll
  for (int a = 0; a < 4; a++)
#pragma unroll
    for (int bq = 0; bq < 4; bq++) acc[a][bq] = fz;
  const int srow = t >> 1, scol = (t & 1) * 32;
#pragma unroll 1
  for (int k0 = 0; k0 < 1024; k0 += 64) {
    const float* sa = Q + (size_t)(m0 + srow) * 1024 + k0 + scol;
    const float* sb = W + (size_t)(n0 + srow) * 1024 + k0 + scol;
#pragma unroll
    for (int c = 0; c < 32; c += 8) {
      s16x8 h, lo;
      cvt8(sa + c, h, lo);
      int si = swz(srow, scol + c);
      *(s16x8*)&Ah[si] = h;
      *(s16x8*)&Al[si] = lo;
    }
#pragma unroll
    for (int c = 0; c < 32; c += 8) {
      s16x8 h, lo;
      cvt8(sb + c, h, lo);
      int si = swz(srow, scol + c);
      *(s16x8*)&Bh[si] = h;
      *(s16x8*)&Bl[si] = lo;
    }
    __syncthreads();
#pragma unroll
    for (int ks = 0; ks < 2; ks++) {
      const int kc = ks * 32 + g * 8;
      s16x8 ah[4], al[4], bh[4], bl[4];
#pragma unroll
      for (int mf = 0; mf < 4; mf++) {
        int si = swz(wm * 64 + mf * 16 + ln, kc);
        ah[mf] = *(s16x8*)&Ah[si];
        al[mf] = *(s16x8*)&Al[si];
      }
#pragma unroll
      for (int nf = 0; nf < 4; nf++) {
        int si = swz(wn * 64 + nf * 16 + ln, kc);
        bh[nf] = *(s16x8*)&Bh[si];
        bl[nf] = *(s16x8*)&Bl[si];
      }
#pragma unroll
      for (int mf = 0; mf < 4; mf++)
#pragma unroll
        for (int nf = 0; nf < 4; nf++) {
          acc[mf][nf] = MFMA16(ah[mf], bh[nf], acc[mf][nf]);
          acc[mf][nf] = MFMA16(ah[mf], bl[nf], acc[mf][nf]);
          acc[mf][nf] = MFMA16(al[mf], bh[nf], acc[mf][nf]);
        }
    }
    __syncthreads();
  }
#pragma unroll
  for (int nf = 0; nf < 4; nf++) {
    const int col = n0 + wn * 64 + nf * 16 + ln;
    const float bv = bias[col];
#pragma unroll
    for (int mf = 0; mf < 4; mf++)
#pragma unroll
      for (int r = 0; r < 4; r++) {
        const int row = m0 + wm * 64 + mf * 16 + g * 4 + r;
        float v = acc[mf][nf][r] + bv;
        qf[(size_t)row * 1024 + col] = v > 0.f ? v : 0.f;
      }
  }
}

__global__ __launch_bounds__(512, 2) void k_attn(const float* __restrict__ Key,
                                                 const float* __restrict__ mask,
                                                 float* __restrict__ dout) {
  __shared__ __align__(16) short qh[64 * 64], qlo[64 * 64], kh[128 * 64], klo[128 * 64];
  __shared__ float mask_s[1024];
  __shared__ float red[4][64];
  const int t = threadIdx.x;
  const int qt = blockIdx.x, b = blockIdx.y;
  const int q0 = qt * 64;
  const int w = t >> 6, l = t & 63, wm = w >> 2, wn = w & 3, g = l >> 4, ln = l & 15;
  for (int i = t; i < 1024; i += 512) mask_s[i] = mask[b * 1024 + i];
  const f32x4 fz = {0.f, 0.f, 0.f, 0.f};
  f32x4 acc[8][2][2];
#pragma unroll
  for (int kt = 0; kt < 8; kt++)
#pragma unroll
    for (int mf = 0; mf < 2; mf++)
#pragma unroll
      for (int nf = 0; nf < 2; nf++) acc[kt][mf][nf] = fz;
  const float* qfb = dout + (size_t)(b * 1024 + q0) * 1024;
  const float* kb = Key + (size_t)b * 1024 * 1024;
  const int qrow = t >> 3, qcol = (t & 7) * 8;
  const int krow = t >> 2, kcol0 = (t & 3) * 16;
#pragma unroll 1
  for (int dc = 0; dc < 16; dc++) {
    {
      s16x8 h, lo;
      cvt8(qfb + (size_t)qrow * 1024 + dc * 64 + qcol, h, lo);
      int si = swz(qrow, qcol);
      *(s16x8*)&qh[si] = h;
      *(s16x8*)&qlo[si] = lo;
    }
#pragma unroll
    for (int kt = 0; kt < 8; kt++) {
      {
        const float* s = kb + (size_t)(kt * 128 + krow) * 1024 + dc * 64 + kcol0;
        s16x8 h, lo;
        cvt8(s, h, lo);
        int si = swz(krow, kcol0);
        *(s16x8*)&kh[si] = h;
        *(s16x8*)&klo[si] = lo;
        cvt8(s + 8, h, lo);
        si = swz(krow, kcol0 + 8);
        *(s16x8*)&kh[si] = h;
        *(s16x8*)&klo[si] = lo;
      }
      __syncthreads();
#pragma unroll
      for (int ks = 0; ks < 2; ks++) {
        const int kc = ks * 32 + g * 8;
        s16x8 ah[2], al2[2], bh[2], bl[2];
#pragma unroll
        for (int mf = 0; mf < 2; mf++) {
          int si = swz(wm * 32 + mf * 16 + ln, kc);
          ah[mf] = *(s16x8*)&qh[si];
          al2[mf] = *(s16x8*)&qlo[si];
        }
#pragma unroll
        for (int nf = 0; nf < 2; nf++) {
          int si = swz(wn * 32 + nf * 16 + ln, kc);
          bh[nf] = *(s16x8*)&kh[si];
          bl[nf] = *(s16x8*)&klo[si];
        }
#pragma unroll
        for (int mf = 0; mf < 2; mf++)
#pragma unroll
          for (int nf = 0; nf < 2; nf++) {
            acc[kt][mf][nf] = MFMA16(ah[mf], bh[nf], acc[kt][mf][nf]);
            acc[kt][mf][nf] = MFMA16(ah[mf], bl[nf], acc[kt][mf][nf]);
            acc[kt][mf][nf] = MFMA16(al2[mf], bh[nf], acc[kt][mf][nf]);
          }
      }
      __syncthreads();
    }
  }
  float rmax[2][4];
#pragma unroll
  for (int mf = 0; mf < 2; mf++)
#pragma unroll
    for (int r = 0; r < 4; r++) rmax[mf][r] = -1e30f;
#pragma unroll
  for (int kt = 0; kt < 8; kt++)
#pragma unroll
    for (int nf = 0; nf < 2; nf++) {
      const int k = kt * 128 + wn * 32 + nf * 16 + ln;
      const bool mk = mask_s[k] != 0.f;
#pragma unroll
      for (int mf = 0; mf < 2; mf++)
#pragma unroll
        for (int r = 0; r < 4; r++)
          if (mk) rmax[mf][r] = fmaxf(rmax[mf][r], acc[kt][mf][nf][r]);
    }
#pragma unroll
  for (int off = 1; off < 16; off <<= 1)
#pragma unroll
    for (int mf = 0; mf < 2; mf++)
#pragma unroll
      for (int r = 0; r < 4; r++) rmax[mf][r] = fmaxf(rmax[mf][r], __shfl_xor(rmax[mf][r], off));
  if (ln == 0) {
#pragma unroll
    for (int mf = 0; mf < 2; mf++)
#pragma unroll
      for (int r = 0; r < 4; r++) red[wn][wm * 32 + mf * 16 + g * 4 + r] = rmax[mf][r];
  }
  __syncthreads();
#pragma unroll
  for (int mf = 0; mf < 2; mf++)
#pragma unroll
    for (int r = 0; r < 4; r++) {
      const int row = wm * 32 + mf * 16 + g * 4 + r;
      rmax[mf][r] = fmaxf(fmaxf(red[0][row], red[1][row]), fmaxf(red[2][row], red[3][row]));
    }
  __syncthreads();
  float rsum[2][4];
#pragma unroll
  for (int mf = 0; mf < 2; mf++)
#pragma unroll
    for (int r = 0; r < 4; r++) rsum[mf][r] = 0.f;
#pragma unroll
  for (int kt = 0; kt < 8; kt++)
#pragma unroll
    for (int nf = 0; nf < 2; nf++) {
      const int k = kt * 128 + wn * 32 + nf * 16 + ln;
      const bool mk = mask_s[k] != 0.f;
#pragma unroll
      for (int mf = 0; mf < 2; mf++)
#pragma unroll
        for (int r = 0; r < 4; r++)
          if (mk) rsum[mf][r] += __expf(acc[kt][mf][nf][r] - rmax[mf][r]);
    }
#pragma unroll
  for (int off = 1; off < 16; off <<= 1)
#pragma unroll
    for (int mf = 0; mf < 2; mf++)
#pragma unroll
      for (int r = 0; r < 4; r++) rsum[mf][r] += __shfl_xor(rsum[mf][r], off);
  if (ln == 0) {
#pragma unroll
    for (int mf = 0; mf < 2; mf++)
#pragma unroll
      for (int r = 0; r < 4; r++) red[wn][wm * 32 + mf * 16 + g * 4 + r] = rsum[mf][r];
  }
  __syncthreads();
  float rinv[2][4];
#pragma unroll
  for (int mf = 0; mf < 2; mf++)
#pragma unroll
    for (int r = 0; r < 4; r++) {
      const int row = wm * 32 + mf * 16 + g * 4 + r;
      rinv[mf][r] = 1.f / (red[0][row] + red[1][row] + red[2][row] + red[3][row]);
    }
  char* oc = (char*)dout;
#pragma unroll
  for (int kt = 0; kt < 8; kt++)
#pragma unroll
    for (int nf = 0; nf < 2; nf++) {
      const int k = kt * 128 + wn * 32 + nf * 16 + ln;
      const bool mk = mask_s[k] != 0.f;
#pragma unroll
      for (int mf = 0; mf < 2; mf++)
#pragma unroll
        for (int r = 0; r < 4; r++) {
          const int q = q0 + wm * 32 + mf * 16 + g * 4 + r;
          float p = mk ? __expf(acc[kt][mf][nf][r] - rmax[mf][r]) * rinv[mf][r] : 0.f;
          *(unsigned short*)(oc + (size_t)(b * 1024 + q) * 4096 + 2048 + k * 2) = f2bf(p);
        }
    }
}

__global__ __launch_bounds__(512, 2) void k_pv(const float* __restrict__ Key,
                                               float* __restrict__ dout, const int dh) {
  __shared__ __align__(16) short P[128 * 64];
  __shared__ __align__(16) short KT[512 * 64];
  const int t = threadIdx.x;
  const int qt = blockIdx.x, b = blockIdx.y;
  const int q0 = qt * 128, d0 = dh * 512;
  const int w = t >> 6, l = t & 63, wm = w >> 2, wd = w & 3, g = l >> 4, ln = l & 15;
  const f32x4 fz = {0.f, 0.f, 0.f, 0.f};
  f32x4 acc[4][8];
#pragma unroll
  for (int a = 0; a < 4; a++)
#pragma unroll
    for (int bq = 0; bq < 8; bq++) acc[a][bq] = fz;
  const char* ab = (const char*)dout;
  const int prow = t >> 2, pc0 = (t & 3) * 16;
#pragma unroll 1
  for (int k0 = 0; k0 < 1024; k0 += 64) {
    {
      const unsigned short* s =
          (const unsigned short*)(ab + (size_t)(b * 1024 + q0 + prow) * 4096 + 2048) + k0 + pc0;
      s16x8 p0 = *(const s16x8*)s, p1 = *(const s16x8*)(s + 8);
      *(s16x8*)&P[swz(prow, pc0)] = p0;
      *(s16x8*)&P[swz(prow, pc0 + 8)] = p1;
    }
    {
      const float* ksrc = Key + (size_t)b * 1024 * 1024 + (size_t)k0 * 1024 + d0 + t;
#pragma unroll
      for (int kg = 0; kg < 8; kg++) {
        s16x8 h;
#pragma unroll
        for (int jx = 0; jx < 8; jx++) h[jx] = (short)f2bf(ksrc[(size_t)(kg * 8 + jx) * 1024]);
        *(s16x8*)&KT[swz(t, kg * 8)] = h;
      }
    }
    __syncthreads();
#pragma unroll
    for (int ks = 0; ks < 2; ks++) {
      const int kc = ks * 32 + g * 8;
      s16x8 a[4], bb[8];
#pragma unroll
      for (int mf = 0; mf < 4; mf++) a[mf] = *(s16x8*)&P[swz(wm * 64 + mf * 16 + ln, kc)];
#pragma unroll
      for (int nf = 0; nf < 8; nf++) bb[nf] = *(s16x8*)&KT[swz(wd * 128 + nf * 16 + ln, kc)];
#pragma unroll
      for (int mf = 0; mf < 4; mf++)
#pragma unroll
        for (int nf = 0; nf < 8; nf++) acc[mf][nf] = MFMA16(a[mf], bb[nf], acc[mf][nf]);
    }
    __syncthreads();
  }
#pragma unroll
  for (int mf = 0; mf < 4; mf++)
#pragma unroll
    for (int nf = 0; nf < 8; nf++)
#pragma unroll
      for (int r = 0; r < 4; r++) {
        const int q = q0 + wm * 64 + mf * 16 + g * 4 + r;
        const int d = d0 + wd * 128 + nf * 16 + ln;
        dout[(size_t)(b * 1024 + q) * 1024 + d] = acc[mf][nf][r];
      }
}

extern "C" void kernel_launch(void* const* d_in, const int* in_sizes, int n_in,
                              void* d_out, int out_size, void* d_ws, size_t ws_size,
                              hipStream_t stream) {
  const float* Q = (const float*)d_in[0];
  const float* K = (const float*)d_in[1];
  const float* M = (const float*)d_in[2];
  const float* W = (const float*)d_in[3];
  const float* bias = (const float*)d_in[4];
  float* out = (float*)d_out;
  char* wsb = (char*)d_ws;
  (void)in_sizes; (void)n_in; (void)out_size;

  if (ws_size >= WS_TIER_A) {
    unsigned short* Khi = (unsigned short*)(wsb + OFF_KHI);
    unsigned short* Klo = (unsigned short*)(wsb + OFF_KLO);
    unsigned short* KhiT = (unsigned short*)(wsb + OFF_KHIT);
    unsigned short* Qhi = (unsigned short*)(wsb + OFF_QHI);
    unsigned short* Qlo = (unsigned short*)(wsb + OFF_QLO);
    unsigned short* Whi = (unsigned short*)(wsb + OFF_WHI);
    unsigned short* Wlo = (unsigned short*)(wsb + OFF_WLO);
    float* Sf = (float*)(wsb + OFF_QHI);  // 128MB, Q planes dead after qf2
    unsigned short* Pw = Klo;             // dead after sgemm8
    k_cvt_all<<<25088, 256, 0, stream>>>(K, Khi, Klo, KhiT, Q, Qhi, Qlo, W, Whi, Wlo);
    k_qf2<<<dim3(256, 8), 256, 0, stream>>>(Qhi, Qlo, Whi, Wlo, bias, out);
    k_sgemm8<<<512, 512, 0, stream>>>(Khi, Klo, (const unsigned short*)out, Sf);
    k_softmax<<<32768, 256, 0, stream>>>(Sf, M, Pw);
    k_pv2<<<dim3(8, 32, 2), 512, 0, stream>>>(KhiT, Pw, out);
  } else {
    k_qf<<<dim3(256, 8), 256, 0, stream>>>(Q, W, bias, out);
    k_attn<<<dim3(16, 32), 512, 0, stream>>>(K, M, out);
    k_pv<<<dim3(8, 32), 512, 0, stream>>>(K, out, 0);
    k_pv<<<dim3(8, 32), 512, 0, stream>>>(K, out, 1);
  }
}

// Round 13
// 712.971 us; speedup vs baseline: 1.0017x; 1.0017x over previous
//
#include <hip/hip_runtime.h>
#include <hip/hip_bf16.h>

// WordSentAtt: qf = relu(Q@W^T + b); S = qf@K^T (masked); attn = softmax; O = attn@K
// B=32, Lq=Lk=D=1024, f32 in/out. Split-bf16 (hi/lo) MFMA for qf and S.
// R12: (1) k_sgemm8 -> BK=32 double-buffer: LDS 64KB -> 2 blocks/CU (m114
//   cross-block overlap; sgemm8 was the only GEMM stuck at 1 block/CU and the
//   only one below qf2). Swizzle adapted to 4 16B-slots (slot = g ^ (row&3)),
//   source pre-swizzled (rule 21). R9's issue order kept (A-loads then stage:
//   stage youngest -> A-waits leave it in flight).
//   (2) cvt_k + cvt_qw merged into one launch (k_cvt_all).

typedef __attribute__((ext_vector_type(4))) float f32x4;
typedef __attribute__((ext_vector_type(8))) short s16x8;
typedef __attribute__((ext_vector_type(4))) short s16x4;

#define MFMA16(a, b, c) __builtin_amdgcn_mfma_f32_16x16x32_bf16((a), (b), (c), 0, 0, 0)

__device__ __forceinline__ unsigned short f2bf(float x) {
  unsigned u = __builtin_bit_cast(unsigned, x);
  return (unsigned short)((u + 0x7FFFu + ((u >> 16) & 1u)) >> 16);
}
__device__ __forceinline__ float bf2f(unsigned short h) {
  return __builtin_bit_cast(float, ((unsigned)h) << 16);
}
__device__ __forceinline__ int swz(int row, int col) {
  return (row * 64 + col) ^ ((row & 7) << 3);
}
__device__ __forceinline__ void cvt8(const float* __restrict__ s, s16x8& h8, s16x8& l8) {
  f32x4 a = *(const f32x4*)s;
  f32x4 b = *(const f32x4*)(s + 4);
#pragma unroll
  for (int i = 0; i < 8; i++) {
    float v = (i < 4) ? a[i] : b[i - 4];
    unsigned short hu = f2bf(v);
    unsigned short lu = f2bf(v - bf2f(hu));
    h8[i] = (short)hu;
    l8[i] = (short)lu;
  }
}
__device__ __forceinline__ void gld16(const void* g, void* lds) {
  __builtin_amdgcn_global_load_lds((const __attribute__((address_space(1))) unsigned int*)g,
                                   (__attribute__((address_space(3))) unsigned int*)lds, 16, 0, 0);
}

// ws layout (bytes)
#define OFF_KHI 0ULL
#define OFF_KLO 67108864ULL   // dead after sgemm8 -> P bf16
#define OFF_KHIT 134217728ULL
#define OFF_QHI 201326592ULL  // Qhi; Q planes dead after qf2 -> S f32 (128MB)
#define OFF_QLO 268435456ULL  // Qlo
#define OFF_WHI 335544320ULL
#define OFF_WLO 337641472ULL
#define WS_TIER_A 339738624ULL
#define QA_LO 33554432ULL  // u16 offset of lo plane inside d_out frag layout

// ================= merged pre-convert kernel =================
// blocks [0,8192): K -> Khi/Klo/KhiT (16x16x32 tiling); [8192,25088): Q/W planes.
__global__ __launch_bounds__(256) void k_cvt_all(const float* __restrict__ K,
                                                 unsigned short* __restrict__ Khi,
                                                 unsigned short* __restrict__ Klo,
                                                 unsigned short* __restrict__ KhiT,
                                                 const float* __restrict__ Q,
                                                 unsigned short* __restrict__ Qhi,
                                                 unsigned short* __restrict__ Qlo,
                                                 const float* __restrict__ W,
                                                 unsigned short* __restrict__ Whi,
                                                 unsigned short* __restrict__ Wlo) {
  __shared__ unsigned T[64 * 65];
  const int bid = blockIdx.x;
  const int t = threadIdx.x;
  if (bid < 8192) {
    const int db0 = (bid & 15) * 64, kb0 = ((bid >> 4) & 15) * 64, b = bid >> 8;
    const size_t base = (size_t)b * 1024 * 1024;
#pragma unroll
    for (int i = 0; i < 2; i++) {
      const int r = (t >> 3) + i * 32, c0 = (t & 7) * 8;
      s16x8 h, l;
      cvt8(K + base + (size_t)(kb0 + r) * 1024 + db0 + c0, h, l);
      *(s16x8*)(Khi + base + (size_t)(kb0 + r) * 1024 + db0 + c0) = h;
      *(s16x8*)(Klo + base + (size_t)(kb0 + r) * 1024 + db0 + c0) = l;
#pragma unroll
      for (int j = 0; j < 8; j++)
        T[r * 65 + c0 + j] = ((unsigned)(unsigned short)h[j] << 16) | (unsigned short)l[j];
    }
    __syncthreads();
#pragma unroll
    for (int i = 0; i < 2; i++) {
      const int rd = (t >> 3) + i * 32, ck0 = (t & 7) * 8;
      s16x8 h;
#pragma unroll
      for (int j = 0; j < 8; j++) h[j] = (short)(unsigned short)(T[(ck0 + j) * 65 + rd] >> 16);
      *(s16x8*)(KhiT + base + (size_t)(db0 + rd) * 1024 + kb0 + ck0) = h;
    }
  } else {
    const int i = (bid - 8192) * 256 + t;
    s16x8 h, l;
    if (i < 4194304) {
      cvt8(Q + (size_t)i * 8, h, l);
      *(s16x8*)(Qhi + (size_t)i * 8) = h;
      *(s16x8*)(Qlo + (size_t)i * 8) = l;
    } else {
      int j = i - 4194304;
      if (j < 131072) {
        cvt8(W + (size_t)j * 8, h, l);
        *(s16x8*)(Whi + (size_t)j * 8) = h;
        *(s16x8*)(Wlo + (size_t)j * 8) = l;
      }
    }
  }
}

// ================= qf GEMM -> fragment-ordered output (R9/R11 version) ========
__global__ __launch_bounds__(256, 2) void k_qf2(const unsigned short* __restrict__ Qhi,
                                                const unsigned short* __restrict__ Qlo,
                                                const unsigned short* __restrict__ Whi,
                                                const unsigned short* __restrict__ Wlo,
                                                const float* __restrict__ bias,
                                                float* __restrict__ outp) {
  __shared__ __align__(16) unsigned short Ah[128 * 64], Al[128 * 64], Bh[128 * 64], Bl[128 * 64];
  const int t = threadIdx.x;
  const int i = blockIdx.x + blockIdx.y * 256;
  const int x = i & 7, j = i >> 3;
  const int n0 = (j & 7) * 128;
  const int m0 = (x * 32 + (j >> 3)) * 128;
  const int w = t >> 6, l = t & 63, wm = w >> 1, wn = w & 1, g = l >> 4, ln = l & 15;
  const int lrow = l >> 3, lc8 = (l & 7) * 8;
  const f32x4 fz = {0.f, 0.f, 0.f, 0.f};
  f32x4 acc[4][4];
#pragma unroll
  for (int a = 0; a < 4; a++)
#pragma unroll
    for (int bq = 0; bq < 4; bq++) acc[a][bq] = fz;
#pragma unroll 1
  for (int k0 = 0; k0 < 1024; k0 += 64) {
#pragma unroll
    for (int jj = 0; jj < 4; jj++) {
      const int ch = w * 4 + jj;
      const int row = ch * 8 + lrow;
      const int sc = lc8 ^ (lrow << 3);
      gld16(Qhi + (size_t)(m0 + row) * 1024 + k0 + sc, &Ah[ch * 512]);
      gld16(Qlo + (size_t)(m0 + row) * 1024 + k0 + sc, &Al[ch * 512]);
      gld16(Whi + (size_t)(n0 + row) * 1024 + k0 + sc, &Bh[ch * 512]);
      gld16(Wlo + (size_t)(n0 + row) * 1024 + k0 + sc, &Bl[ch * 512]);
    }
    __syncthreads();
#pragma unroll
    for (int ks = 0; ks < 2; ks++) {
      const int kc = ks * 32 + g * 8;
      s16x8 ah[4], al[4], bh[4], bl[4];
#pragma unroll
      for (int mf = 0; mf < 4; mf++) {
        const int row = wm * 64 + mf * 16 + ln;
        const int idx = row * 64 + (kc ^ ((row & 7) << 3));
        ah[mf] = *(const s16x8*)&Ah[idx];
        al[mf] = *(const s16x8*)&Al[idx];
      }
#pragma unroll
      for (int nf = 0; nf < 4; nf++) {
        const int row = wn * 64 + nf * 16 + ln;
        const int idx = row * 64 + (kc ^ ((row & 7) << 3));
        bh[nf] = *(const s16x8*)&Bh[idx];
        bl[nf] = *(const s16x8*)&Bl[idx];
      }
#pragma unroll
      for (int mf = 0; mf < 4; mf++)
#pragma unroll
        for (int nf = 0; nf < 4; nf++) {
          acc[mf][nf] = MFMA16(ah[mf], bh[nf], acc[mf][nf]);
          acc[mf][nf] = MFMA16(ah[mf], bl[nf], acc[mf][nf]);
          acc[mf][nf] = MFMA16(al[mf], bh[nf], acc[mf][nf]);
        }
    }
    __syncthreads();
  }
  unsigned short* qA = (unsigned short*)outp;
#pragma unroll
  for (int nf = 0; nf < 4; nf++) {
    const int c = n0 + wn * 64 + nf * 16 + ln;
    const float bv = bias[c];
    const int kchunk = c >> 5, lhib = ((c >> 3) & 3) << 4, jj = c & 7;
#pragma unroll
    for (int mf = 0; mf < 4; mf++)
#pragma unroll
      for (int r = 0; r < 4; r++) {
        const int R = m0 + wm * 64 + mf * 16 + g * 4 + r;
        float v = acc[mf][nf][r] + bv;
        v = v > 0.f ? v : 0.f;
        unsigned short h = f2bf(v);
        const size_t fo = (((size_t)(R >> 4) * 32 + kchunk) * 64 + ((R & 15) + lhib)) * 8 + jj;
        qA[fo] = h;
        qA[QA_LO + fo] = f2bf(v - bf2f(h));
      }
  }
}

// ================= S = qf @ K^T, 256x256, BK=32 dbuf, 2 blocks/CU (R12) =======
__global__ __launch_bounds__(512, 2) void k_sgemm8(const unsigned short* __restrict__ Khi,
                                                   const unsigned short* __restrict__ Klo,
                                                   const unsigned short* __restrict__ qA,
                                                   float* __restrict__ Sf) {
  __shared__ __align__(16) unsigned short Bh[2][256 * 32], Bl[2][256 * 32];  // 64KB
  const int t = threadIdx.x;
  const int i = blockIdx.x;
  const int x = i & 7, jj = i >> 3;
  const int b = x * 4 + (jj >> 4);
  const int qt = (jj >> 2) & 3, nt = jj & 3;
  const int q0g = b * 1024 + qt * 256;
  const int k0g = nt * 256;
  const int w = t >> 6, l = t & 63, wm = w >> 2, wn = w & 3, g = l >> 4, ln = l & 15;
  const size_t kbase = (size_t)b * 1024 * 1024;
  const int qb0 = (q0g >> 4) + wm * 8;
  // stage geometry: chunk ch covers rows [ch*16, ch*16+16); lane l -> row
  // ch*16 + (l>>2), src 16B-slot (l&3)^((l>>2)&3) (pre-swizzle, rule 21)
  const int srow_in = l >> 2;                      // 0..15 within chunk
  const int sslot = (l & 3) ^ (srow_in & 3);       // swizzled source slot
  const f32x4 fz = {0.f, 0.f, 0.f, 0.f};
  f32x4 acc[8][4];
#pragma unroll
  for (int a = 0; a < 8; a++)
#pragma unroll
    for (int bq = 0; bq < 4; bq++) acc[a][bq] = fz;

  auto stageB = [&](int buf, int dc) {
#pragma unroll
    for (int jj2 = 0; jj2 < 2; jj2++) {
      const int ch = w * 2 + jj2;         // 0..15
      const int row = ch * 16 + srow_in;  // 0..255
      const size_t go = kbase + (size_t)(k0g + row) * 1024 + dc * 32 + sslot * 8;
      gld16(Khi + go, &Bh[buf][ch * 512]);
      gld16(Klo + go, &Bl[buf][ch * 512]);
    }
  };

  stageB(0, 0);
#pragma unroll 1
  for (int dc = 0; dc < 32; dc++) {
    const int cur = dc & 1;
    asm volatile("s_waitcnt vmcnt(0)" ::: "memory");
    __builtin_amdgcn_s_barrier();
    __builtin_amdgcn_sched_barrier(0);
    // A-frags first, stage after (stage youngest -> A-wait leaves it in flight)
    s16x8 ah[8], al[8];
#pragma unroll
    for (int mf = 0; mf < 8; mf++) {
      const size_t fo = (((size_t)(qb0 + mf) * 32 + dc) * 64 + l) * 8;
      ah[mf] = *(const s16x8*)(qA + fo);
      al[mf] = *(const s16x8*)(qA + QA_LO + fo);
    }
    __builtin_amdgcn_sched_barrier(0);
    if (dc < 31) stageB(cur ^ 1, dc + 1);
    __builtin_amdgcn_sched_barrier(0);
    s16x8 bh[4], bl[4];
#pragma unroll
    for (int nf = 0; nf < 4; nf++) {
      const int row = wn * 64 + nf * 16 + ln;
      const int idx = row * 32 + ((g ^ (row & 3)) * 8);
      bh[nf] = *(const s16x8*)&Bh[cur][idx];
      bl[nf] = *(const s16x8*)&Bl[cur][idx];
    }
    __builtin_amdgcn_s_setprio(1);
#pragma unroll
    for (int mf = 0; mf < 8; mf++)
#pragma unroll
      for (int nf = 0; nf < 4; nf++) {
        acc[mf][nf] = MFMA16(ah[mf], bh[nf], acc[mf][nf]);
        acc[mf][nf] = MFMA16(ah[mf], bl[nf], acc[mf][nf]);
        acc[mf][nf] = MFMA16(al[mf], bh[nf], acc[mf][nf]);
      }
    __builtin_amdgcn_s_setprio(0);
  }
  // epilogue: S as f32 (single plane)
#pragma unroll
  for (int mf = 0; mf < 8; mf++)
#pragma unroll
    for (int nf = 0; nf < 4; nf++) {
      const int colS = k0g + wn * 64 + nf * 16 + ln;
#pragma unroll
      for (int r = 0; r < 4; r++) {
        const int rowS = q0g + wm * 128 + mf * 16 + g * 4 + r;
        Sf[(size_t)rowS * 1024 + colS] = acc[mf][nf][r];
      }
    }
}

// ================= masked softmax, streaming (f32 input) ======================
__global__ __launch_bounds__(256) void k_softmax(const float* __restrict__ Sf,
                                                 const float* __restrict__ mask,
                                                 unsigned short* __restrict__ P) {
  __shared__ float red[2][4];
  const int row = blockIdx.x;
  const int b = row >> 10;
  const int t = threadIdx.x, w = t >> 6, l = t & 63;
  const size_t base = (size_t)row * 1024 + t * 4;
  const f32x4 sv = *(const f32x4*)(Sf + base);
  const f32x4 mk = *(const f32x4*)(mask + b * 1024 + t * 4);
  float s[4];
  bool um[4];
#pragma unroll
  for (int j = 0; j < 4; j++) {
    s[j] = sv[j];
    um[j] = mk[j] != 0.f;
  }
  float mx = -1e30f;
#pragma unroll
  for (int j = 0; j < 4; j++)
    if (um[j]) mx = fmaxf(mx, s[j]);
#pragma unroll
  for (int off = 1; off < 64; off <<= 1) mx = fmaxf(mx, __shfl_xor(mx, off));
  if (l == 0) red[0][w] = mx;
  __syncthreads();
  mx = fmaxf(fmaxf(red[0][0], red[0][1]), fmaxf(red[0][2], red[0][3]));
  float e[4];
  float sum = 0.f;
#pragma unroll
  for (int j = 0; j < 4; j++) {
    e[j] = um[j] ? __expf(s[j] - mx) : 0.f;
    sum += e[j];
  }
#pragma unroll
  for (int off = 1; off < 64; off <<= 1) sum += __shfl_xor(sum, off);
  if (l == 0) red[1][w] = sum;
  __syncthreads();
  const float rinv = 1.f / (red[1][0] + red[1][1] + red[1][2] + red[1][3]);
  s16x4 o;
#pragma unroll
  for (int j = 0; j < 4; j++) o[j] = (short)f2bf(e[j] * rinv);
  *(s16x4*)(P + base) = o;
}

// ================= O = attn @ K via KhiT (unchanged) ==========================
__global__ __launch_bounds__(512, 1) void k_pv2(const unsigned short* __restrict__ KhiT,
                                                const unsigned short* __restrict__ attnw,
                                                float* __restrict__ dout) {
  __shared__ __align__(16) unsigned short Pb[2][128 * 64];
  __shared__ __align__(16) unsigned short KTb[2][512 * 64];
  const int t = threadIdx.x;
  const int i = blockIdx.y * 8 + blockIdx.x;
  const int x = i & 7, jj = i >> 3;
  const int b = x * 4 + (jj >> 3), qt = jj & 7;
  const int q0 = qt * 128, d0 = blockIdx.z * 512;
  const int w = t >> 6, l = t & 63, wm = w >> 2, wd = w & 3, g = l >> 4, ln = l & 15;
  const int lrow = l >> 3, lc8 = (l & 7) * 8, sc = lc8 ^ (lrow << 3);
  const f32x4 fz = {0.f, 0.f, 0.f, 0.f};
  f32x4 acc[4][8];
#pragma unroll
  for (int a = 0; a < 4; a++)
#pragma unroll
    for (int bq = 0; bq < 8; bq++) acc[a][bq] = fz;
  const size_t kbase = (size_t)b * 1024 * 1024;

  auto stageP = [&](int buf, int k0) {
#pragma unroll
    for (int jj2 = 0; jj2 < 2; jj2++) {
      const int ch = w * 2 + jj2;
      const int row = ch * 8 + lrow;
      gld16(attnw + (size_t)(b * 1024 + q0 + row) * 1024 + k0 + sc, &Pb[buf][ch * 512]);
    }
  };
  auto stageKT = [&](int buf, int k0) {
#pragma unroll
    for (int jj2 = 0; jj2 < 8; jj2++) {
      const int ch = w * 8 + jj2;
      const int row = ch * 8 + lrow;
      gld16(KhiT + kbase + (size_t)(d0 + row) * 1024 + k0 + sc, &KTb[buf][ch * 512]);
    }
  };

  stageP(0, 0);
  stageKT(0, 0);
#pragma unroll 1
  for (int s = 0; s < 16; s++) {
    asm volatile("s_waitcnt vmcnt(0)" ::: "memory");
    __builtin_amdgcn_s_barrier();
    __builtin_amdgcn_sched_barrier(0);
    if (s < 15) {
      stageP((s + 1) & 1, (s + 1) * 64);
      stageKT((s + 1) & 1, (s + 1) * 64);
    }
    const int cur = s & 1;
    __builtin_amdgcn_s_setprio(1);
#pragma unroll
    for (int ks = 0; ks < 2; ks++) {
      const int kc = ks * 32 + g * 8;
      s16x8 a[4], bb[8];
#pragma unroll
      for (int mf = 0; mf < 4; mf++) {
        const int row = wm * 64 + mf * 16 + ln;
        a[mf] = *(const s16x8*)&Pb[cur][row * 64 + (kc ^ ((row & 7) << 3))];
      }
#pragma unroll
      for (int nf = 0; nf < 8; nf++) {
        const int row = wd * 128 + nf * 16 + ln;
        bb[nf] = *(const s16x8*)&KTb[cur][row * 64 + (kc ^ ((row & 7) << 3))];
      }
#pragma unroll
      for (int mf = 0; mf < 4; mf++)
#pragma unroll
        for (int nf = 0; nf < 8; nf++) acc[mf][nf] = MFMA16(a[mf], bb[nf], acc[mf][nf]);
    }
    __builtin_amdgcn_s_setprio(0);
  }
#pragma unroll
  for (int mf = 0; mf < 4; mf++)
#pragma unroll
    for (int nf = 0; nf < 8; nf++)
#pragma unroll
      for (int r = 0; r < 4; r++) {
        const int q = q0 + wm * 64 + mf * 16 + g * 4 + r;
        const int d = d0 + wd * 128 + nf * 16 + ln;
        dout[(size_t)(b * 1024 + q) * 1024 + d] = acc[mf][nf][r];
      }
}

// ================= Tier C: round-1 kernels (fallback, unchanged) =============
__global__ __launch_bounds__(256, 2) void k_qf(const float* __restrict__ Q,
                                               const float* __restrict__ W,
                                               const float* __restrict__ bias,
                                               float* __restrict__ qf) {
  __shared__ __align__(16) short Ah[128 * 64], Al[128 * 64], Bh[128 * 64], Bl[128 * 64];
  const int t = threadIdx.x;
  const int m0 = blockIdx.x * 128, n0 = blockIdx.y * 128;
  const int w = t >> 6, l = t & 63, wm = w >> 1, wn = w & 1, g = l >> 4, ln = l & 15;
  const f32x4 fz = {0.f, 0.f, 0.f, 0.f};
  f32x4 acc[4][4];
#pragma unroll
  for (int a = 0; a < 4; a++)
#pragma unroll
    for (int bq = 0; bq < 4; bq++) acc[a][bq] = fz;
  const int srow = t >> 1, scol = (t & 1) * 32;
#pragma unroll 1
  for (int k0 = 0; k0 < 1024; k0 += 64) {
    const float* sa = Q + (size_t)(m0 + srow) * 1024 + k0 + scol;
    const float* sb = W + (size_t)(n0 + srow) * 1024 + k0 + scol;
#pragma unroll
    for (int c = 0; c < 32; c += 8) {
      s16x8 h, lo;
      cvt8(sa + c, h, lo);
      int si = swz(srow, scol + c);
      *(s16x8*)&Ah[si] = h;
      *(s16x8*)&Al[si] = lo;
    }
#pragma unroll
    for (int c = 0; c < 32; c += 8) {
      s16x8 h, lo;
      cvt8(sb + c, h, lo);
      int si = swz(srow, scol + c);
      *(s16x8*)&Bh[si] = h;
      *(s16x8*)&Bl[si] = lo;
    }
    __syncthreads();
#pragma unroll
    for (int ks = 0; ks < 2; ks++) {
      const int kc = ks * 32 + g * 8;
      s16x8 ah[4], al[4], bh[4], bl[4];
#pragma unroll
      for (int mf = 0; mf < 4; mf++) {
        int si = swz(wm * 64 + mf * 16 + ln, kc);
        ah[mf] = *(s16x8*)&Ah[si];
        al[mf] = *(s16x8*)&Al[si];
      }
#pragma unroll
      for (int nf = 0; nf < 4; nf++) {
        int si = swz(wn * 64 + nf * 16 + ln, kc);
        bh[nf] = *(s16x8*)&Bh[si];
        bl[nf] = *(s16x8*)&Bl[si];
      }
#pragma unroll
      for (int mf = 0; mf < 4; mf++)
#pragma unroll
        for (int nf = 0; nf < 4; nf++) {
          acc[mf][nf] = MFMA16(ah[mf], bh[nf], acc[mf][nf]);
          acc[mf][nf] = MFMA16(ah[mf], bl[nf], acc[mf][nf]);
          acc[mf][nf] = MFMA16(al[mf], bh[nf], acc[mf][nf]);
        }
    }
    __syncthreads();
  }
#pragma unroll
  for (int nf = 0; nf < 4; nf++) {
    const int col = n0 + wn * 64 + nf * 16 + ln;
    const float bv = bias[col];
#pragma unroll
    for (int mf = 0; mf < 4; mf++)
#pragma unroll
      for (int r = 0; r < 4; r++) {
        const int row = m0 + wm * 64 + mf * 16 + g * 4 + r;
        float v = acc[mf][nf][r] + bv;
        qf[(size_t)row * 1024 + col] = v > 0.f ? v : 0.f;
      }
  }
}

__global__ __launch_bounds__(512, 2) void k_attn(const float* __restrict__ Key,
                                                 const float* __restrict__ mask,
                                                 float* __restrict__ dout) {
  __shared__ __align__(16) short qh[64 * 64], qlo[64 * 64], kh[128 * 64], klo[128 * 64];
  __shared__ float mask_s[1024];
  __shared__ float red[4][64];
  const int t = threadIdx.x;
  const int qt = blockIdx.x, b = blockIdx.y;
  const int q0 = qt * 64;
  const int w = t >> 6, l = t & 63, wm = w >> 2, wn = w & 3, g = l >> 4, ln = l & 15;
  for (int i = t; i < 1024; i += 512) mask_s[i] = mask[b * 1024 + i];
  const f32x4 fz = {0.f, 0.f, 0.f, 0.f};
  f32x4 acc[8][2][2];
#pragma unroll
  for (int kt = 0; kt < 8; kt++)
#pragma unroll
    for (int mf = 0; mf < 2; mf++)
#pragma unroll
      for (int nf = 0; nf < 2; nf++) acc[kt][mf][nf] = fz;
  const float* qfb = dout + (size_t)(b * 1024 + q0) * 1024;
  const float* kb = Key + (size_t)b * 1024 * 1024;
  const int qrow = t >> 3, qcol = (t & 7) * 8;
  const int krow = t >> 2, kcol0 = (t & 3) * 16;
#pragma unroll 1
  for (int dc = 0; dc < 16; dc++) {
    {
      s16x8 h, lo;
      cvt8(qfb + (size_t)qrow * 1024 + dc * 64 + qcol, h, lo);
      int si = swz(qrow, qcol);
      *(s16x8*)&qh[si] = h;
      *(s16x8*)&qlo[si] = lo;
    }
#pragma unroll
    for (int kt = 0; kt < 8; kt++) {
      {
        const float* s = kb + (size_t)(kt * 128 + krow) * 1024 + dc * 64 + kcol0;
        s16x8 h, lo;
        cvt8(s, h, lo);
        int si = swz(krow, kcol0);
        *(s16x8*)&kh[si] = h;
        *(s16x8*)&klo[si] = lo;
        cvt8(s + 8, h, lo);
        si = swz(krow, kcol0 + 8);
        *(s16x8*)&kh[si] = h;
        *(s16x8*)&klo[si] = lo;
      }
      __syncthreads();
#pragma unroll
      for (int ks = 0; ks < 2; ks++) {
        const int kc = ks * 32 + g * 8;
        s16x8 ah[2], al2[2], bh[2], bl[2];
#pragma unroll
        for (int mf = 0; mf < 2; mf++) {
          int si = swz(wm * 32 + mf * 16 + ln, kc);
          ah[mf] = *(s16x8*)&qh[si];
          al2[mf] = *(s16x8*)&qlo[si];
        }
#pragma unroll
        for (int nf = 0; nf < 2; nf++) {
          int si = swz(wn * 32 + nf * 16 + ln, kc);
          bh[nf] = *(s16x8*)&kh[si];
          bl[nf] = *(s16x8*)&klo[si];
        }
#pragma unroll
        for (int mf = 0; mf < 2; mf++)
#pragma unroll
          for (int nf = 0; nf < 2; nf++) {
            acc[kt][mf][nf] = MFMA16(ah[mf], bh[nf], acc[kt][mf][nf]);
            acc[kt][mf][nf] = MFMA16(ah[mf], bl[nf], acc[kt][mf][nf]);
            acc[kt][mf][nf] = MFMA16(al2[mf], bh[nf], acc[kt][mf][nf]);
          }
      }
      __syncthreads();
    }
  }
  float rmax[2][4];
#pragma unroll
  for (int mf = 0; mf < 2; mf++)
#pragma unroll
    for (int r = 0; r < 4; r++) rmax[mf][r] = -1e30f;
#pragma unroll
  for (int kt = 0; kt < 8; kt++)
#pragma unroll
    for (int nf = 0; nf < 2; nf++) {
      const int k = kt * 128 + wn * 32 + nf * 16 + ln;
      const bool mk = mask_s[k] != 0.f;
#pragma unroll
      for (int mf = 0; mf < 2; mf++)
#pragma unroll
        for (int r = 0; r < 4; r++)
          if (mk) rmax[mf][r] = fmaxf(rmax[mf][r], acc[kt][mf][nf][r]);
    }
#pragma unroll
  for (int off = 1; off < 16; off <<= 1)
#pragma unroll
    for (int mf = 0; mf < 2; mf++)
#pragma unroll
      for (int r = 0; r < 4; r++) rmax[mf][r] = fmaxf(rmax[mf][r], __shfl_xor(rmax[mf][r], off));
  if (ln == 0) {
#pragma unroll
    for (int mf = 0; mf < 2; mf++)
#pragma unroll
      for (int r = 0; r < 4; r++) red[wn][wm * 32 + mf * 16 + g * 4 + r] = rmax[mf][r];
  }
  __syncthreads();
#pragma unroll
  for (int mf = 0; mf < 2; mf++)
#pragma unroll
    for (int r = 0; r < 4; r++) {
      const int row = wm * 32 + mf * 16 + g * 4 + r;
      rmax[mf][r] = fmaxf(fmaxf(red[0][row], red[1][row]), fmaxf(red[2][row], red[3][row]));
    }
  __syncthreads();
  float rsum[2][4];
#pragma unroll
  for (int mf = 0; mf < 2; mf++)
#pragma unroll
    for (int r = 0; r < 4; r++) rsum[mf][r] = 0.f;
#pragma unroll
  for (int kt = 0; kt < 8; kt++)
#pragma unroll
    for (int nf = 0; nf < 2; nf++) {
      const int k = kt * 128 + wn * 32 + nf * 16 + ln;
      const bool mk = mask_s[k] != 0.f;
#pragma unroll
      for (int mf = 0; mf < 2; mf++)
#pragma unroll
        for (int r = 0; r < 4; r++)
          if (mk) rsum[mf][r] += __expf(acc[kt][mf][nf][r] - rmax[mf][r]);
    }
#pragma unroll
  for (int off = 1; off < 16; off <<= 1)
#pragma unroll
    for (int mf = 0; mf < 2; mf++)
#pragma unroll
      for (int r = 0; r < 4; r++) rsum[mf][r] += __shfl_xor(rsum[mf][r], off);
  if (ln == 0) {
#pragma unroll
    for (int mf = 0; mf < 2; mf++)
#pragma unroll
      for (int r = 0; r < 4; r++) red[wn][wm * 32 + mf * 16 + g * 4 + r] = rsum[mf][r];
  }
  __syncthreads();
  float rinv[2][4];
#pragma unroll
  for (int mf = 0; mf < 2; mf++)
#pragma unroll
    for (int r = 0; r < 4; r++) {
      const int row = wm * 32 + mf * 16 + g * 4 + r;
      rinv[mf][r] = 1.f / (red[0][row] + red[1][row] + red[2][row] + red[3][row]);
    }
  char* oc = (char*)dout;
#pragma unroll
  for (int kt = 0; kt < 8; kt++)
#pragma unroll
    for (int nf = 0; nf < 2; nf++) {
      const int k = kt * 128 + wn * 32 + nf * 16 + ln;
      const bool mk = mask_s[k] != 0.f;
#pragma unroll
      for (int mf = 0; mf < 2; mf++)
#pragma unroll
        for (int r = 0; r < 4; r++) {
          const int q = q0 + wm * 32 + mf * 16 + g * 4 + r;
          float p = mk ? __expf(acc[kt][mf][nf][r] - rmax[mf][r]) * rinv[mf][r] : 0.f;
          *(unsigned short*)(oc + (size_t)(b * 1024 + q) * 4096 + 2048 + k * 2) = f2bf(p);
        }
    }
}

__global__ __launch_bounds__(512, 2) void k_pv(const float* __restrict__ Key,
                                               float* __restrict__ dout, const int dh) {
  __shared__ __align__(16) short P[128 * 64];
  __shared__ __align__(16) short KT[512 * 64];
  const int t = threadIdx.x;
  const int qt = blockIdx.x, b = blockIdx.y;
  const int q0 = qt * 128, d0 = dh * 512;
  const int w = t >> 6, l = t & 63, wm = w >> 2, wd = w & 3, g = l >> 4, ln = l & 15;
  const f32x4 fz = {0.f, 0.f, 0.f, 0.f};
  f32x4 acc[4][8];
#pragma unroll
  for (int a = 0; a < 4; a++)
#pragma unroll
    for (int bq = 0; bq < 8; bq++) acc[a][bq] = fz;
  const char* ab = (const char*)dout;
  const int prow = t >> 2, pc0 = (t & 3) * 16;
#pragma unroll 1
  for (int k0 = 0; k0 < 1024; k0 += 64) {
    {
      const unsigned short* s =
          (const unsigned short*)(ab + (size_t)(b * 1024 + q0 + prow) * 4096 + 2048) + k0 + pc0;
      s16x8 p0 = *(const s16x8*)s, p1 = *(const s16x8*)(s + 8);
      *(s16x8*)&P[swz(prow, pc0)] = p0;
      *(s16x8*)&P[swz(prow, pc0 + 8)] = p1;
    }
    {
      const float* ksrc = Key + (size_t)b * 1024 * 1024 + (size_t)k0 * 1024 + d0 + t;
#pragma unroll
      for (int kg = 0; kg < 8; kg++) {
        s16x8 h;
#pragma unroll
        for (int jx = 0; jx < 8; jx++) h[jx] = (short)f2bf(ksrc[(size_t)(kg * 8 + jx) * 1024]);
        *(s16x8*)&KT[swz(t, kg * 8)] = h;
      }
    }
    __syncthreads();
#pragma unroll
    for (int ks = 0; ks < 2; ks++) {
      const int kc = ks * 32 + g * 8;
      s16x8 a[4], bb[8];
#pragma unroll
      for (int mf = 0; mf < 4; mf++) a[mf] = *(s16x8*)&P[swz(wm * 64 + mf * 16 + ln, kc)];
#pragma unroll
      for (int nf = 0; nf < 8; nf++) bb[nf] = *(s16x8*)&KT[swz(wd * 128 + nf * 16 + ln, kc)];
#pragma unroll
      for (int mf = 0; mf < 4; mf++)
#pragma unroll
        for (int nf = 0; nf < 8; nf++) acc[mf][nf] = MFMA16(a[mf], bb[nf], acc[mf][nf]);
    }
    __syncthreads();
  }
#pragma unroll
  for (int mf = 0; mf < 4; mf++)
#pragma unroll
    for (int nf = 0; nf < 8; nf++)
#pragma unroll
      for (int r = 0; r < 4; r++) {
        const int q = q0 + wm * 64 + mf * 16 + g * 4 + r;
        const int d = d0 + wd * 128 + nf * 16 + ln;
        dout[(size_t)(b * 1024 + q) * 1024 + d] = acc[mf][nf][r];
      }
}

extern "C" void kernel_launch(void* const* d_in, const int* in_sizes, int n_in,
                              void* d_out, int out_size, void* d_ws, size_t ws_size,
                              hipStream_t stream) {
  const float* Q = (const float*)d_in[0];
  const float* K = (const float*)d_in[1];
  const float* M = (const float*)d_in[2];
  const float* W = (const float*)d_in[3];
  const float* bias = (const float*)d_in[4];
  float* out = (float*)d_out;
  char* wsb = (char*)d_ws;
  (void)in_sizes; (void)n_in; (void)out_size;

  if (ws_size >= WS_TIER_A) {
    unsigned short* Khi = (unsigned short*)(wsb + OFF_KHI);
    unsigned short* Klo = (unsigned short*)(wsb + OFF_KLO);
    unsigned short* KhiT = (unsigned short*)(wsb + OFF_KHIT);
    unsigned short* Qhi = (unsigned short*)(wsb + OFF_QHI);
    unsigned short* Qlo = (unsigned short*)(wsb + OFF_QLO);
    unsigned short* Whi = (unsigned short*)(wsb + OFF_WHI);
    unsigned short* Wlo = (unsigned short*)(wsb + OFF_WLO);
    float* Sf = (float*)(wsb + OFF_QHI);  // 128MB, Q planes dead after qf2
    unsigned short* Pw = Klo;             // dead after sgemm8
    k_cvt_all<<<25088, 256, 0, stream>>>(K, Khi, Klo, KhiT, Q, Qhi, Qlo, W, Whi, Wlo);
    k_qf2<<<dim3(256, 8), 256, 0, stream>>>(Qhi, Qlo, Whi, Wlo, bias, out);
    k_sgemm8<<<512, 512, 0, stream>>>(Khi, Klo, (const unsigned short*)out, Sf);
    k_softmax<<<32768, 256, 0, stream>>>(Sf, M, Pw);
    k_pv2<<<dim3(8, 32, 2), 512, 0, stream>>>(KhiT, Pw, out);
  } else {
    k_qf<<<dim3(256, 8), 256, 0, stream>>>(Q, W, bias, out);
    k_attn<<<dim3(16, 32), 512, 0, stream>>>(K, M, out);
    k_pv<<<dim3(8, 32), 512, 0, stream>>>(K, out, 0);
    k_pv<<<dim3(8, 32), 512, 0, stream>>>(K, out, 1);
  }
}

// Round 14
// 687.412 us; speedup vs baseline: 1.0390x; 1.0372x over previous
//
#include <hip/hip_runtime.h>
#include <hip/hip_bf16.h>

// WordSentAtt: qf = relu(Q@W^T + b); S = qf@K^T (masked); attn = softmax; O = attn@K
// B=32, Lq=Lk=D=1024, f32 in/out. Split-bf16 (hi/lo) MFMA for qf and S.
// R13 = best measured config (R11, 692us): sgemm8 BK=64 (R9 issue order,
//   228us, 0 conflicts), qf2 (228us), f32-S plane, streaming softmax, pv2.
//   Merged k_cvt_all kept from R12 (neutral, one fewer launch).
//   R12 lesson: sgemm8's occupancy is REGISTER-bound (128 acc + ~120 VGPR ~
//   248/lane -> 2 waves/SIMD -> 1 block/CU); shrinking LDS to 64KB cannot
//   raise it and BK=32 halved barrier amortization (+4.2M bank conflicts).

typedef __attribute__((ext_vector_type(4))) float f32x4;
typedef __attribute__((ext_vector_type(8))) short s16x8;
typedef __attribute__((ext_vector_type(4))) short s16x4;

#define MFMA16(a, b, c) __builtin_amdgcn_mfma_f32_16x16x32_bf16((a), (b), (c), 0, 0, 0)

__device__ __forceinline__ unsigned short f2bf(float x) {
  unsigned u = __builtin_bit_cast(unsigned, x);
  return (unsigned short)((u + 0x7FFFu + ((u >> 16) & 1u)) >> 16);
}
__device__ __forceinline__ float bf2f(unsigned short h) {
  return __builtin_bit_cast(float, ((unsigned)h) << 16);
}
__device__ __forceinline__ int swz(int row, int col) {
  return (row * 64 + col) ^ ((row & 7) << 3);
}
__device__ __forceinline__ void cvt8(const float* __restrict__ s, s16x8& h8, s16x8& l8) {
  f32x4 a = *(const f32x4*)s;
  f32x4 b = *(const f32x4*)(s + 4);
#pragma unroll
  for (int i = 0; i < 8; i++) {
    float v = (i < 4) ? a[i] : b[i - 4];
    unsigned short hu = f2bf(v);
    unsigned short lu = f2bf(v - bf2f(hu));
    h8[i] = (short)hu;
    l8[i] = (short)lu;
  }
}
__device__ __forceinline__ void gld16(const void* g, void* lds) {
  __builtin_amdgcn_global_load_lds((const __attribute__((address_space(1))) unsigned int*)g,
                                   (__attribute__((address_space(3))) unsigned int*)lds, 16, 0, 0);
}

// ws layout (bytes)
#define OFF_KHI 0ULL
#define OFF_KLO 67108864ULL   // dead after sgemm8 -> P bf16
#define OFF_KHIT 134217728ULL
#define OFF_QHI 201326592ULL  // Qhi; Q planes dead after qf2 -> S f32 (128MB)
#define OFF_QLO 268435456ULL  // Qlo
#define OFF_WHI 335544320ULL
#define OFF_WLO 337641472ULL
#define WS_TIER_A 339738624ULL
#define QA_LO 33554432ULL  // u16 offset of lo plane inside d_out frag layout

// ================= merged pre-convert kernel =================
__global__ __launch_bounds__(256) void k_cvt_all(const float* __restrict__ K,
                                                 unsigned short* __restrict__ Khi,
                                                 unsigned short* __restrict__ Klo,
                                                 unsigned short* __restrict__ KhiT,
                                                 const float* __restrict__ Q,
                                                 unsigned short* __restrict__ Qhi,
                                                 unsigned short* __restrict__ Qlo,
                                                 const float* __restrict__ W,
                                                 unsigned short* __restrict__ Whi,
                                                 unsigned short* __restrict__ Wlo) {
  __shared__ unsigned T[64 * 65];
  const int bid = blockIdx.x;
  const int t = threadIdx.x;
  if (bid < 8192) {
    const int db0 = (bid & 15) * 64, kb0 = ((bid >> 4) & 15) * 64, b = bid >> 8;
    const size_t base = (size_t)b * 1024 * 1024;
#pragma unroll
    for (int i = 0; i < 2; i++) {
      const int r = (t >> 3) + i * 32, c0 = (t & 7) * 8;
      s16x8 h, l;
      cvt8(K + base + (size_t)(kb0 + r) * 1024 + db0 + c0, h, l);
      *(s16x8*)(Khi + base + (size_t)(kb0 + r) * 1024 + db0 + c0) = h;
      *(s16x8*)(Klo + base + (size_t)(kb0 + r) * 1024 + db0 + c0) = l;
#pragma unroll
      for (int j = 0; j < 8; j++)
        T[r * 65 + c0 + j] = ((unsigned)(unsigned short)h[j] << 16) | (unsigned short)l[j];
    }
    __syncthreads();
#pragma unroll
    for (int i = 0; i < 2; i++) {
      const int rd = (t >> 3) + i * 32, ck0 = (t & 7) * 8;
      s16x8 h;
#pragma unroll
      for (int j = 0; j < 8; j++) h[j] = (short)(unsigned short)(T[(ck0 + j) * 65 + rd] >> 16);
      *(s16x8*)(KhiT + base + (size_t)(db0 + rd) * 1024 + kb0 + ck0) = h;
    }
  } else {
    const int i = (bid - 8192) * 256 + t;
    s16x8 h, l;
    if (i < 4194304) {
      cvt8(Q + (size_t)i * 8, h, l);
      *(s16x8*)(Qhi + (size_t)i * 8) = h;
      *(s16x8*)(Qlo + (size_t)i * 8) = l;
    } else {
      int j = i - 4194304;
      if (j < 131072) {
        cvt8(W + (size_t)j * 8, h, l);
        *(s16x8*)(Whi + (size_t)j * 8) = h;
        *(s16x8*)(Wlo + (size_t)j * 8) = l;
      }
    }
  }
}

// ================= qf GEMM -> fragment-ordered output =========================
__global__ __launch_bounds__(256, 2) void k_qf2(const unsigned short* __restrict__ Qhi,
                                                const unsigned short* __restrict__ Qlo,
                                                const unsigned short* __restrict__ Whi,
                                                const unsigned short* __restrict__ Wlo,
                                                const float* __restrict__ bias,
                                                float* __restrict__ outp) {
  __shared__ __align__(16) unsigned short Ah[128 * 64], Al[128 * 64], Bh[128 * 64], Bl[128 * 64];
  const int t = threadIdx.x;
  const int i = blockIdx.x + blockIdx.y * 256;
  const int x = i & 7, j = i >> 3;
  const int n0 = (j & 7) * 128;
  const int m0 = (x * 32 + (j >> 3)) * 128;
  const int w = t >> 6, l = t & 63, wm = w >> 1, wn = w & 1, g = l >> 4, ln = l & 15;
  const int lrow = l >> 3, lc8 = (l & 7) * 8;
  const f32x4 fz = {0.f, 0.f, 0.f, 0.f};
  f32x4 acc[4][4];
#pragma unroll
  for (int a = 0; a < 4; a++)
#pragma unroll
    for (int bq = 0; bq < 4; bq++) acc[a][bq] = fz;
#pragma unroll 1
  for (int k0 = 0; k0 < 1024; k0 += 64) {
#pragma unroll
    for (int jj = 0; jj < 4; jj++) {
      const int ch = w * 4 + jj;
      const int row = ch * 8 + lrow;
      const int sc = lc8 ^ (lrow << 3);
      gld16(Qhi + (size_t)(m0 + row) * 1024 + k0 + sc, &Ah[ch * 512]);
      gld16(Qlo + (size_t)(m0 + row) * 1024 + k0 + sc, &Al[ch * 512]);
      gld16(Whi + (size_t)(n0 + row) * 1024 + k0 + sc, &Bh[ch * 512]);
      gld16(Wlo + (size_t)(n0 + row) * 1024 + k0 + sc, &Bl[ch * 512]);
    }
    __syncthreads();
#pragma unroll
    for (int ks = 0; ks < 2; ks++) {
      const int kc = ks * 32 + g * 8;
      s16x8 ah[4], al[4], bh[4], bl[4];
#pragma unroll
      for (int mf = 0; mf < 4; mf++) {
        const int row = wm * 64 + mf * 16 + ln;
        const int idx = row * 64 + (kc ^ ((row & 7) << 3));
        ah[mf] = *(const s16x8*)&Ah[idx];
        al[mf] = *(const s16x8*)&Al[idx];
      }
#pragma unroll
      for (int nf = 0; nf < 4; nf++) {
        const int row = wn * 64 + nf * 16 + ln;
        const int idx = row * 64 + (kc ^ ((row & 7) << 3));
        bh[nf] = *(const s16x8*)&Bh[idx];
        bl[nf] = *(const s16x8*)&Bl[idx];
      }
#pragma unroll
      for (int mf = 0; mf < 4; mf++)
#pragma unroll
        for (int nf = 0; nf < 4; nf++) {
          acc[mf][nf] = MFMA16(ah[mf], bh[nf], acc[mf][nf]);
          acc[mf][nf] = MFMA16(ah[mf], bl[nf], acc[mf][nf]);
          acc[mf][nf] = MFMA16(al[mf], bh[nf], acc[mf][nf]);
        }
    }
    __syncthreads();
  }
  unsigned short* qA = (unsigned short*)outp;
#pragma unroll
  for (int nf = 0; nf < 4; nf++) {
    const int c = n0 + wn * 64 + nf * 16 + ln;
    const float bv = bias[c];
    const int kchunk = c >> 5, lhib = ((c >> 3) & 3) << 4, jj = c & 7;
#pragma unroll
    for (int mf = 0; mf < 4; mf++)
#pragma unroll
      for (int r = 0; r < 4; r++) {
        const int R = m0 + wm * 64 + mf * 16 + g * 4 + r;
        float v = acc[mf][nf][r] + bv;
        v = v > 0.f ? v : 0.f;
        unsigned short h = f2bf(v);
        const size_t fo = (((size_t)(R >> 4) * 32 + kchunk) * 64 + ((R & 15) + lhib)) * 8 + jj;
        qA[fo] = h;
        qA[QA_LO + fo] = f2bf(v - bf2f(h));
      }
  }
}

// ================= S = qf @ K^T, 256x256, BK=64 (R9/R11 order) ================
__global__ __launch_bounds__(512, 1) void k_sgemm8(const unsigned short* __restrict__ Khi,
                                                   const unsigned short* __restrict__ Klo,
                                                   const unsigned short* __restrict__ qA,
                                                   float* __restrict__ Sf) {
  __shared__ __align__(16) unsigned short Bh[2][256 * 64], Bl[2][256 * 64];
  const int t = threadIdx.x;
  const int i = blockIdx.x;
  const int x = i & 7, jj = i >> 3;
  const int b = x * 4 + (jj >> 4);
  const int qt = (jj >> 2) & 3, nt = jj & 3;
  const int q0g = b * 1024 + qt * 256;
  const int k0g = nt * 256;
  const int w = t >> 6, l = t & 63, wm = w >> 2, wn = w & 3, g = l >> 4, ln = l & 15;
  const int lrow = l >> 3, lc8 = (l & 7) * 8, sc = lc8 ^ (lrow << 3);
  const size_t kbase = (size_t)b * 1024 * 1024;
  const int qb0 = (q0g >> 4) + wm * 8;
  const f32x4 fz = {0.f, 0.f, 0.f, 0.f};
  f32x4 acc[8][4];
#pragma unroll
  for (int a = 0; a < 8; a++)
#pragma unroll
    for (int bq = 0; bq < 4; bq++) acc[a][bq] = fz;

  auto stageB = [&](int buf, int dc) {
#pragma unroll
    for (int jj2 = 0; jj2 < 4; jj2++) {
      const int ch = w * 4 + jj2;
      const int row = ch * 8 + lrow;
      const size_t go = kbase + (size_t)(k0g + row) * 1024 + dc * 64 + sc;
      gld16(Khi + go, &Bh[buf][ch * 512]);
      gld16(Klo + go, &Bl[buf][ch * 512]);
    }
  };

  stageB(0, 0);
#pragma unroll 1
  for (int dc = 0; dc < 16; dc++) {
    const int cur = dc & 1;
    asm volatile("s_waitcnt vmcnt(0)" ::: "memory");
    __builtin_amdgcn_s_barrier();
    __builtin_amdgcn_sched_barrier(0);
#pragma unroll
    for (int ks = 0; ks < 2; ks++) {
      s16x8 ah[8], al[8];
#pragma unroll
      for (int mf = 0; mf < 8; mf++) {
        const size_t fo = (((size_t)(qb0 + mf) * 32 + dc * 2 + ks) * 64 + l) * 8;
        ah[mf] = *(const s16x8*)(qA + fo);
        al[mf] = *(const s16x8*)(qA + QA_LO + fo);
      }
      if (ks == 0 && dc < 15) stageB(cur ^ 1, dc + 1);
      const int kc = ks * 32 + g * 8;
      s16x8 bh[4], bl[4];
#pragma unroll
      for (int nf = 0; nf < 4; nf++) {
        const int row = wn * 64 + nf * 16 + ln;
        const int idx = row * 64 + (kc ^ ((row & 7) << 3));
        bh[nf] = *(const s16x8*)&Bh[cur][idx];
        bl[nf] = *(const s16x8*)&Bl[cur][idx];
      }
      __builtin_amdgcn_s_setprio(1);
#pragma unroll
      for (int mf = 0; mf < 8; mf++)
#pragma unroll
        for (int nf = 0; nf < 4; nf++) {
          acc[mf][nf] = MFMA16(ah[mf], bh[nf], acc[mf][nf]);
          acc[mf][nf] = MFMA16(ah[mf], bl[nf], acc[mf][nf]);
          acc[mf][nf] = MFMA16(al[mf], bh[nf], acc[mf][nf]);
        }
      __builtin_amdgcn_s_setprio(0);
    }
  }
  // epilogue: S as f32 (single plane)
#pragma unroll
  for (int mf = 0; mf < 8; mf++)
#pragma unroll
    for (int nf = 0; nf < 4; nf++) {
      const int colS = k0g + wn * 64 + nf * 16 + ln;
#pragma unroll
      for (int r = 0; r < 4; r++) {
        const int rowS = q0g + wm * 128 + mf * 16 + g * 4 + r;
        Sf[(size_t)rowS * 1024 + colS] = acc[mf][nf][r];
      }
    }
}

// ================= masked softmax, streaming (f32 input) ======================
__global__ __launch_bounds__(256) void k_softmax(const float* __restrict__ Sf,
                                                 const float* __restrict__ mask,
                                                 unsigned short* __restrict__ P) {
  __shared__ float red[2][4];
  const int row = blockIdx.x;
  const int b = row >> 10;
  const int t = threadIdx.x, w = t >> 6, l = t & 63;
  const size_t base = (size_t)row * 1024 + t * 4;
  const f32x4 sv = *(const f32x4*)(Sf + base);
  const f32x4 mk = *(const f32x4*)(mask + b * 1024 + t * 4);
  float s[4];
  bool um[4];
#pragma unroll
  for (int j = 0; j < 4; j++) {
    s[j] = sv[j];
    um[j] = mk[j] != 0.f;
  }
  float mx = -1e30f;
#pragma unroll
  for (int j = 0; j < 4; j++)
    if (um[j]) mx = fmaxf(mx, s[j]);
#pragma unroll
  for (int off = 1; off < 64; off <<= 1) mx = fmaxf(mx, __shfl_xor(mx, off));
  if (l == 0) red[0][w] = mx;
  __syncthreads();
  mx = fmaxf(fmaxf(red[0][0], red[0][1]), fmaxf(red[0][2], red[0][3]));
  float e[4];
  float sum = 0.f;
#pragma unroll
  for (int j = 0; j < 4; j++) {
    e[j] = um[j] ? __expf(s[j] - mx) : 0.f;
    sum += e[j];
  }
#pragma unroll
  for (int off = 1; off < 64; off <<= 1) sum += __shfl_xor(sum, off);
  if (l == 0) red[1][w] = sum;
  __syncthreads();
  const float rinv = 1.f / (red[1][0] + red[1][1] + red[1][2] + red[1][3]);
  s16x4 o;
#pragma unroll
  for (int j = 0; j < 4; j++) o[j] = (short)f2bf(e[j] * rinv);
  *(s16x4*)(P + base) = o;
}

// ================= O = attn @ K via KhiT ======================================
__global__ __launch_bounds__(512, 1) void k_pv2(const unsigned short* __restrict__ KhiT,
                                                const unsigned short* __restrict__ attnw,
                                                float* __restrict__ dout) {
  __shared__ __align__(16) unsigned short Pb[2][128 * 64];
  __shared__ __align__(16) unsigned short KTb[2][512 * 64];
  const int t = threadIdx.x;
  const int i = blockIdx.y * 8 + blockIdx.x;
  const int x = i & 7, jj = i >> 3;
  const int b = x * 4 + (jj >> 3), qt = jj & 7;
  const int q0 = qt * 128, d0 = blockIdx.z * 512;
  const int w = t >> 6, l = t & 63, wm = w >> 2, wd = w & 3, g = l >> 4, ln = l & 15;
  const int lrow = l >> 3, lc8 = (l & 7) * 8, sc = lc8 ^ (lrow << 3);
  const f32x4 fz = {0.f, 0.f, 0.f, 0.f};
  f32x4 acc[4][8];
#pragma unroll
  for (int a = 0; a < 4; a++)
#pragma unroll
    for (int bq = 0; bq < 8; bq++) acc[a][bq] = fz;
  const size_t kbase = (size_t)b * 1024 * 1024;

  auto stageP = [&](int buf, int k0) {
#pragma unroll
    for (int jj2 = 0; jj2 < 2; jj2++) {
      const int ch = w * 2 + jj2;
      const int row = ch * 8 + lrow;
      gld16(attnw + (size_t)(b * 1024 + q0 + row) * 1024 + k0 + sc, &Pb[buf][ch * 512]);
    }
  };
  auto stageKT = [&](int buf, int k0) {
#pragma unroll
    for (int jj2 = 0; jj2 < 8; jj2++) {
      const int ch = w * 8 + jj2;
      const int row = ch * 8 + lrow;
      gld16(KhiT + kbase + (size_t)(d0 + row) * 1024 + k0 + sc, &KTb[buf][ch * 512]);
    }
  };

  stageP(0, 0);
  stageKT(0, 0);
#pragma unroll 1
  for (int s = 0; s < 16; s++) {
    asm volatile("s_waitcnt vmcnt(0)" ::: "memory");
    __builtin_amdgcn_s_barrier();
    __builtin_amdgcn_sched_barrier(0);
    if (s < 15) {
      stageP((s + 1) & 1, (s + 1) * 64);
      stageKT((s + 1) & 1, (s + 1) * 64);
    }
    const int cur = s & 1;
    __builtin_amdgcn_s_setprio(1);
#pragma unroll
    for (int ks = 0; ks < 2; ks++) {
      const int kc = ks * 32 + g * 8;
      s16x8 a[4], bb[8];
#pragma unroll
      for (int mf = 0; mf < 4; mf++) {
        const int row = wm * 64 + mf * 16 + ln;
        a[mf] = *(const s16x8*)&Pb[cur][row * 64 + (kc ^ ((row & 7) << 3))];
      }
#pragma unroll
      for (int nf = 0; nf < 8; nf++) {
        const int row = wd * 128 + nf * 16 + ln;
        bb[nf] = *(const s16x8*)&KTb[cur][row * 64 + (kc ^ ((row & 7) << 3))];
      }
#pragma unroll
      for (int mf = 0; mf < 4; mf++)
#pragma unroll
        for (int nf = 0; nf < 8; nf++) acc[mf][nf] = MFMA16(a[mf], bb[nf], acc[mf][nf]);
    }
    __builtin_amdgcn_s_setprio(0);
  }
#pragma unroll
  for (int mf = 0; mf < 4; mf++)
#pragma unroll
    for (int nf = 0; nf < 8; nf++)
#pragma unroll
      for (int r = 0; r < 4; r++) {
        const int q = q0 + wm * 64 + mf * 16 + g * 4 + r;
        const int d = d0 + wd * 128 + nf * 16 + ln;
        dout[(size_t)(b * 1024 + q) * 1024 + d] = acc[mf][nf][r];
      }
}

// ================= Tier C: round-1 kernels (fallback, unchanged) =============
__global__ __launch_bounds__(256, 2) void k_qf(const float* __restrict__ Q,
                                               const float* __restrict__ W,
                                               const float* __restrict__ bias,
                                               float* __restrict__ qf) {
  __shared__ __align__(16) short Ah[128 * 64], Al[128 * 64], Bh[128 * 64], Bl[128 * 64];
  const int t = threadIdx.x;
  const int m0 = blockIdx.x * 128, n0 = blockIdx.y * 128;
  const int w = t >> 6, l = t & 63, wm = w >> 1, wn = w & 1, g = l >> 4, ln = l & 15;
  const f32x4 fz = {0.f, 0.f, 0.f, 0.f};
  f32x4 acc[4][4];
#pragma unroll
  for (int a = 0; a < 4; a++)
#pragma unroll
    for (int bq = 0; bq < 4; bq++) acc[a][bq] = fz;
  const int srow = t >> 1, scol = (t & 1) * 32;
#pragma unroll 1
  for (int k0 = 0; k0 < 1024; k0 += 64) {
    const float* sa = Q + (size_t)(m0 + srow) * 1024 + k0 + scol;
    const float* sb = W + (size_t)(n0 + srow) * 1024 + k0 + scol;
#pragma unroll
    for (int c = 0; c < 32; c += 8) {
      s16x8 h, lo;
      cvt8(sa + c, h, lo);
      int si = swz(srow, scol + c);
      *(s16x8*)&Ah[si] = h;
      *(s16x8*)&Al[si] = lo;
    }
#pragma unroll
    for (int c = 0; c < 32; c += 8) {
      s16x8 h, lo;
      cvt8(sb + c, h, lo);
      int si = swz(srow, scol + c);
      *(s16x8*)&Bh[si] = h;
      *(s16x8*)&Bl[si] = lo;
    }
    __syncthreads();
#pragma unroll
    for (int ks = 0; ks < 2; ks++) {
      const int kc = ks * 32 + g * 8;
      s16x8 ah[4], al[4], bh[4], bl[4];
#pragma unroll
      for (int mf = 0; mf < 4; mf++) {
        int si = swz(wm * 64 + mf * 16 + ln, kc);
        ah[mf] = *(s16x8*)&Ah[si];
        al[mf] = *(s16x8*)&Al[si];
      }
#pragma unroll
      for (int nf = 0; nf < 4; nf++) {
        int si = swz(wn * 64 + nf * 16 + ln, kc);
        bh[nf] = *(s16x8*)&Bh[si];
        bl[nf] = *(s16x8*)&Bl[si];
      }
#pragma unroll
      for (int mf = 0; mf < 4; mf++)
#pragma unroll
        for (int nf = 0; nf < 4; nf++) {
          acc[mf][nf] = MFMA16(ah[mf], bh[nf], acc[mf][nf]);
          acc[mf][nf] = MFMA16(ah[mf], bl[nf], acc[mf][nf]);
          acc[mf][nf] = MFMA16(al[mf], bh[nf], acc[mf][nf]);
        }
    }
    __syncthreads();
  }
#pragma unroll
  for (int nf = 0; nf < 4; nf++) {
    const int col = n0 + wn * 64 + nf * 16 + ln;
    const float bv = bias[col];
#pragma unroll
    for (int mf = 0; mf < 4; mf++)
#pragma unroll
      for (int r = 0; r < 4; r++) {
        const int row = m0 + wm * 64 + mf * 16 + g * 4 + r;
        float v = acc[mf][nf][r] + bv;
        qf[(size_t)row * 1024 + col] = v > 0.f ? v : 0.f;
      }
  }
}

__global__ __launch_bounds__(512, 2) void k_attn(const float* __restrict__ Key,
                                                 const float* __restrict__ mask,
                                                 float* __restrict__ dout) {
  __shared__ __align__(16) short qh[64 * 64], qlo[64 * 64], kh[128 * 64], klo[128 * 64];
  __shared__ float mask_s[1024];
  __shared__ float red[4][64];
  const int t = threadIdx.x;
  const int qt = blockIdx.x, b = blockIdx.y;
  const int q0 = qt * 64;
  const int w = t >> 6, l = t & 63, wm = w >> 2, wn = w & 3, g = l >> 4, ln = l & 15;
  for (int i = t; i < 1024; i += 512) mask_s[i] = mask[b * 1024 + i];
  const f32x4 fz = {0.f, 0.f, 0.f, 0.f};
  f32x4 acc[8][2][2];
#pragma unroll
  for (int kt = 0; kt < 8; kt++)
#pragma unroll
    for (int mf = 0; mf < 2; mf++)
#pragma unroll
      for (int nf = 0; nf < 2; nf++) acc[kt][mf][nf] = fz;
  const float* qfb = dout + (size_t)(b * 1024 + q0) * 1024;
  const float* kb = Key + (size_t)b * 1024 * 1024;
  const int qrow = t >> 3, qcol = (t & 7) * 8;
  const int krow = t >> 2, kcol0 = (t & 3) * 16;
#pragma unroll 1
  for (int dc = 0; dc < 16; dc++) {
    {
      s16x8 h, lo;
      cvt8(qfb + (size_t)qrow * 1024 + dc * 64 + qcol, h, lo);
      int si = swz(qrow, qcol);
      *(s16x8*)&qh[si] = h;
      *(s16x8*)&qlo[si] = lo;
    }
#pragma unroll
    for (int kt = 0; kt < 8; kt++) {
      {
        const float* s = kb + (size_t)(kt * 128 + krow) * 1024 + dc * 64 + kcol0;
        s16x8 h, lo;
        cvt8(s, h, lo);
        int si = swz(krow, kcol0);
        *(s16x8*)&kh[si] = h;
        *(s16x8*)&klo[si] = lo;
        cvt8(s + 8, h, lo);
        si = swz(krow, kcol0 + 8);
        *(s16x8*)&kh[si] = h;
        *(s16x8*)&klo[si] = lo;
      }
      __syncthreads();
#pragma unroll
      for (int ks = 0; ks < 2; ks++) {
        const int kc = ks * 32 + g * 8;
        s16x8 ah[2], al2[2], bh[2], bl[2];
#pragma unroll
        for (int mf = 0; mf < 2; mf++) {
          int si = swz(wm * 32 + mf * 16 + ln, kc);
          ah[mf] = *(s16x8*)&qh[si];
          al2[mf] = *(s16x8*)&qlo[si];
        }
#pragma unroll
        for (int nf = 0; nf < 2; nf++) {
          int si = swz(wn * 32 + nf * 16 + ln, kc);
          bh[nf] = *(s16x8*)&kh[si];
          bl[nf] = *(s16x8*)&klo[si];
        }
#pragma unroll
        for (int mf = 0; mf < 2; mf++)
#pragma unroll
          for (int nf = 0; nf < 2; nf++) {
            acc[kt][mf][nf] = MFMA16(ah[mf], bh[nf], acc[kt][mf][nf]);
            acc[kt][mf][nf] = MFMA16(ah[mf], bl[nf], acc[kt][mf][nf]);
            acc[kt][mf][nf] = MFMA16(al2[mf], bh[nf], acc[kt][mf][nf]);
          }
      }
      __syncthreads();
    }
  }
  float rmax[2][4];
#pragma unroll
  for (int mf = 0; mf < 2; mf++)
#pragma unroll
    for (int r = 0; r < 4; r++) rmax[mf][r] = -1e30f;
#pragma unroll
  for (int kt = 0; kt < 8; kt++)
#pragma unroll
    for (int nf = 0; nf < 2; nf++) {
      const int k = kt * 128 + wn * 32 + nf * 16 + ln;
      const bool mk = mask_s[k] != 0.f;
#pragma unroll
      for (int mf = 0; mf < 2; mf++)
#pragma unroll
        for (int r = 0; r < 4; r++)
          if (mk) rmax[mf][r] = fmaxf(rmax[mf][r], acc[kt][mf][nf][r]);
    }
#pragma unroll
  for (int off = 1; off < 16; off <<= 1)
#pragma unroll
    for (int mf = 0; mf < 2; mf++)
#pragma unroll
      for (int r = 0; r < 4; r++) rmax[mf][r] = fmaxf(rmax[mf][r], __shfl_xor(rmax[mf][r], off));
  if (ln == 0) {
#pragma unroll
    for (int mf = 0; mf < 2; mf++)
#pragma unroll
      for (int r = 0; r < 4; r++) red[wn][wm * 32 + mf * 16 + g * 4 + r] = rmax[mf][r];
  }
  __syncthreads();
#pragma unroll
  for (int mf = 0; mf < 2; mf++)
#pragma unroll
    for (int r = 0; r < 4; r++) {
      const int row = wm * 32 + mf * 16 + g * 4 + r;
      rmax[mf][r] = fmaxf(fmaxf(red[0][row], red[1][row]), fmaxf(red[2][row], red[3][row]));
    }
  __syncthreads();
  float rsum[2][4];
#pragma unroll
  for (int mf = 0; mf < 2; mf++)
#pragma unroll
    for (int r = 0; r < 4; r++) rsum[mf][r] = 0.f;
#pragma unroll
  for (int kt = 0; kt < 8; kt++)
#pragma unroll
    for (int nf = 0; nf < 2; nf++) {
      const int k = kt * 128 + wn * 32 + nf * 16 + ln;
      const bool mk = mask_s[k] != 0.f;
#pragma unroll
      for (int mf = 0; mf < 2; mf++)
#pragma unroll
        for (int r = 0; r < 4; r++)
          if (mk) rsum[mf][r] += __expf(acc[kt][mf][nf][r] - rmax[mf][r]);
    }
#pragma unroll
  for (int off = 1; off < 16; off <<= 1)
#pragma unroll
    for (int mf = 0; mf < 2; mf++)
#pragma unroll
      for (int r = 0; r < 4; r++) rsum[mf][r] += __shfl_xor(rsum[mf][r], off);
  if (ln == 0) {
#pragma unroll
    for (int mf = 0; mf < 2; mf++)
#pragma unroll
      for (int r = 0; r < 4; r++) red[wn][wm * 32 + mf * 16 + g * 4 + r] = rsum[mf][r];
  }
  __syncthreads();
  float rinv[2][4];
#pragma unroll
  for (int mf = 0; mf < 2; mf++)
#pragma unroll
    for (int r = 0; r < 4; r++) {
      const int row = wm * 32 + mf * 16 + g * 4 + r;
      rinv[mf][r] = 1.f / (red[0][row] + red[1][row] + red[2][row] + red[3][row]);
    }
  char* oc = (char*)dout;
#pragma unroll
  for (int kt = 0; kt < 8; kt++)
#pragma unroll
    for (int nf = 0; nf < 2; nf++) {
      const int k = kt * 128 + wn * 32 + nf * 16 + ln;
      const bool mk = mask_s[k] != 0.f;
#pragma unroll
      for (int mf = 0; mf < 2; mf++)
#pragma unroll
        for (int r = 0; r < 4; r++) {
          const int q = q0 + wm * 32 + mf * 16 + g * 4 + r;
          float p = mk ? __expf(acc[kt][mf][nf][r] - rmax[mf][r]) * rinv[mf][r] : 0.f;
          *(unsigned short*)(oc + (size_t)(b * 1024 + q) * 4096 + 2048 + k * 2) = f2bf(p);
        }
    }
}

__global__ __launch_bounds__(512, 2) void k_pv(const float* __restrict__ Key,
                                               float* __restrict__ dout, const int dh) {
  __shared__ __align__(16) short P[128 * 64];
  __shared__ __align__(16) short KT[512 * 64];
  const int t = threadIdx.x;
  const int qt = blockIdx.x, b = blockIdx.y;
  const int q0 = qt * 128, d0 = dh * 512;
  const int w = t >> 6, l = t & 63, wm = w >> 2, wd = w & 3, g = l >> 4, ln = l & 15;
  const f32x4 fz = {0.f, 0.f, 0.f, 0.f};
  f32x4 acc[4][8];
#pragma unroll
  for (int a = 0; a < 4; a++)
#pragma unroll
    for (int bq = 0; bq < 8; bq++) acc[a][bq] = fz;
  const char* ab = (const char*)dout;
  const int prow = t >> 2, pc0 = (t & 3) * 16;
#pragma unroll 1
  for (int k0 = 0; k0 < 1024; k0 += 64) {
    {
      const unsigned short* s =
          (const unsigned short*)(ab + (size_t)(b * 1024 + q0 + prow) * 4096 + 2048) + k0 + pc0;
      s16x8 p0 = *(const s16x8*)s, p1 = *(const s16x8*)(s + 8);
      *(s16x8*)&P[swz(prow, pc0)] = p0;
      *(s16x8*)&P[swz(prow, pc0 + 8)] = p1;
    }
    {
      const float* ksrc = Key + (size_t)b * 1024 * 1024 + (size_t)k0 * 1024 + d0 + t;
#pragma unroll
      for (int kg = 0; kg < 8; kg++) {
        s16x8 h;
#pragma unroll
        for (int jx = 0; jx < 8; jx++) h[jx] = (short)f2bf(ksrc[(size_t)(kg * 8 + jx) * 1024]);
        *(s16x8*)&KT[swz(t, kg * 8)] = h;
      }
    }
    __syncthreads();
#pragma unroll
    for (int ks = 0; ks < 2; ks++) {
      const int kc = ks * 32 + g * 8;
      s16x8 a[4], bb[8];
#pragma unroll
      for (int mf = 0; mf < 4; mf++) a[mf] = *(s16x8*)&P[swz(wm * 64 + mf * 16 + ln, kc)];
#pragma unroll
      for (int nf = 0; nf < 8; nf++) bb[nf] = *(s16x8*)&KT[swz(wd * 128 + nf * 16 + ln, kc)];
#pragma unroll
      for (int mf = 0; mf < 4; mf++)
#pragma unroll
        for (int nf = 0; nf < 8; nf++) acc[mf][nf] = MFMA16(a[mf], bb[nf], acc[mf][nf]);
    }
    __syncthreads();
  }
#pragma unroll
  for (int mf = 0; mf < 4; mf++)
#pragma unroll
    for (int nf = 0; nf < 8; nf++)
#pragma unroll
      for (int r = 0; r < 4; r++) {
        const int q = q0 + wm * 64 + mf * 16 + g * 4 + r;
        const int d = d0 + wd * 128 + nf * 16 + ln;
        dout[(size_t)(b * 1024 + q) * 1024 + d] = acc[mf][nf][r];
      }
}

extern "C" void kernel_launch(void* const* d_in, const int* in_sizes, int n_in,
                              void* d_out, int out_size, void* d_ws, size_t ws_size,
                              hipStream_t stream) {
  const float* Q = (const float*)d_in[0];
  const float* K = (const float*)d_in[1];
  const float* M = (const float*)d_in[2];
  const float* W = (const float*)d_in[3];
  const float* bias = (const float*)d_in[4];
  float* out = (float*)d_out;
  char* wsb = (char*)d_ws;
  (void)in_sizes; (void)n_in; (void)out_size;

  if (ws_size >= WS_TIER_A) {
    unsigned short* Khi = (unsigned short*)(wsb + OFF_KHI);
    unsigned short* Klo = (unsigned short*)(wsb + OFF_KLO);
    unsigned short* KhiT = (unsigned short*)(wsb + OFF_KHIT);
    unsigned short* Qhi = (unsigned short*)(wsb + OFF_QHI);
    unsigned short* Qlo = (unsigned short*)(wsb + OFF_QLO);
    unsigned short* Whi = (unsigned short*)(wsb + OFF_WHI);
    unsigned short* Wlo = (unsigned short*)(wsb + OFF_WLO);
    float* Sf = (float*)(wsb + OFF_QHI);  // 128MB, Q planes dead after qf2
    unsigned short* Pw = Klo;             // dead after sgemm8
    k_cvt_all<<<25088, 256, 0, stream>>>(K, Khi, Klo, KhiT, Q, Qhi, Qlo, W, Whi, Wlo);
    k_qf2<<<dim3(256, 8), 256, 0, stream>>>(Qhi, Qlo, Whi, Wlo, bias, out);
    k_sgemm8<<<512, 512, 0, stream>>>(Khi, Klo, (const unsigned short*)out, Sf);
    k_softmax<<<32768, 256, 0, stream>>>(Sf, M, Pw);
    k_pv2<<<dim3(8, 32, 2), 512, 0, stream>>>(KhiT, Pw, out);
  } else {
    k_qf<<<dim3(256, 8), 256, 0, stream>>>(Q, W, bias, out);
    k_attn<<<dim3(16, 32), 512, 0, stream>>>(K, M, out);
    k_pv<<<dim3(8, 32), 512, 0, stream>>>(K, out, 0);
    k_pv<<<dim3(8, 32), 512, 0, stream>>>(K, out, 1);
  }
}

// Round 15
// 686.203 us; speedup vs baseline: 1.0408x; 1.0018x over previous
//
#include <hip/hip_runtime.h>
#include <hip/hip_bf16.h>

// WordSentAtt: qf = relu(Q@W^T + b); S = qf@K^T (masked); attn = softmax; O = attn@K
// B=32, Lq=Lk=D=1024, f32 in/out. Split-bf16 (hi/lo) MFMA for qf and S.
// R13 = best measured config (R11, 692us): sgemm8 BK=64 (R9 issue order,
//   228us, 0 conflicts), qf2 (228us), f32-S plane, streaming softmax, pv2.
//   Merged k_cvt_all kept from R12 (neutral, one fewer launch).
//   R12 lesson: sgemm8's occupancy is REGISTER-bound (128 acc + ~120 VGPR ~
//   248/lane -> 2 waves/SIMD -> 1 block/CU); shrinking LDS to 64KB cannot
//   raise it and BK=32 halved barrier amortization (+4.2M bank conflicts).

typedef __attribute__((ext_vector_type(4))) float f32x4;
typedef __attribute__((ext_vector_type(8))) short s16x8;
typedef __attribute__((ext_vector_type(4))) short s16x4;

#define MFMA16(a, b, c) __builtin_amdgcn_mfma_f32_16x16x32_bf16((a), (b), (c), 0, 0, 0)

__device__ __forceinline__ unsigned short f2bf(float x) {
  unsigned u = __builtin_bit_cast(unsigned, x);
  return (unsigned short)((u + 0x7FFFu + ((u >> 16) & 1u)) >> 16);
}
__device__ __forceinline__ float bf2f(unsigned short h) {
  return __builtin_bit_cast(float, ((unsigned)h) << 16);
}
__device__ __forceinline__ int swz(int row, int col) {
  return (row * 64 + col) ^ ((row & 7) << 3);
}
__device__ __forceinline__ void cvt8(const float* __restrict__ s, s16x8& h8, s16x8& l8) {
  f32x4 a = *(const f32x4*)s;
  f32x4 b = *(const f32x4*)(s + 4);
#pragma unroll
  for (int i = 0; i < 8; i++) {
    float v = (i < 4) ? a[i] : b[i - 4];
    unsigned short hu = f2bf(v);
    unsigned short lu = f2bf(v - bf2f(hu));
    h8[i] = (short)hu;
    l8[i] = (short)lu;
  }
}
__device__ __forceinline__ void gld16(const void* g, void* lds) {
  __builtin_amdgcn_global_load_lds((const __attribute__((address_space(1))) unsigned int*)g,
                                   (__attribute__((address_space(3))) unsigned int*)lds, 16, 0, 0);
}

// ws layout (bytes)
#define OFF_KHI 0ULL
#define OFF_KLO 67108864ULL   // dead after sgemm8 -> P bf16
#define OFF_KHIT 134217728ULL
#define OFF_QHI 201326592ULL  // Qhi; Q planes dead after qf2 -> S f32 (128MB)
#define OFF_QLO 268435456ULL  // Qlo
#define OFF_WHI 335544320ULL
#define OFF_WLO 337641472ULL
#define WS_TIER_A 339738624ULL
#define QA_LO 33554432ULL  // u16 offset of lo plane inside d_out frag layout

// ================= merged pre-convert kernel =================
__global__ __launch_bounds__(256) void k_cvt_all(const float* __restrict__ K,
                                                 unsigned short* __restrict__ Khi,
                                                 unsigned short* __restrict__ Klo,
                                                 unsigned short* __restrict__ KhiT,
                                                 const float* __restrict__ Q,
                                                 unsigned short* __restrict__ Qhi,
                                                 unsigned short* __restrict__ Qlo,
                                                 const float* __restrict__ W,
                                                 unsigned short* __restrict__ Whi,
                                                 unsigned short* __restrict__ Wlo) {
  __shared__ unsigned T[64 * 65];
  const int bid = blockIdx.x;
  const int t = threadIdx.x;
  if (bid < 8192) {
    const int db0 = (bid & 15) * 64, kb0 = ((bid >> 4) & 15) * 64, b = bid >> 8;
    const size_t base = (size_t)b * 1024 * 1024;
#pragma unroll
    for (int i = 0; i < 2; i++) {
      const int r = (t >> 3) + i * 32, c0 = (t & 7) * 8;
      s16x8 h, l;
      cvt8(K + base + (size_t)(kb0 + r) * 1024 + db0 + c0, h, l);
      *(s16x8*)(Khi + base + (size_t)(kb0 + r) * 1024 + db0 + c0) = h;
      *(s16x8*)(Klo + base + (size_t)(kb0 + r) * 1024 + db0 + c0) = l;
#pragma unroll
      for (int j = 0; j < 8; j++)
        T[r * 65 + c0 + j] = ((unsigned)(unsigned short)h[j] << 16) | (unsigned short)l[j];
    }
    __syncthreads();
#pragma unroll
    for (int i = 0; i < 2; i++) {
      const int rd = (t >> 3) + i * 32, ck0 = (t & 7) * 8;
      s16x8 h;
#pragma unroll
      for (int j = 0; j < 8; j++) h[j] = (short)(unsigned short)(T[(ck0 + j) * 65 + rd] >> 16);
      *(s16x8*)(KhiT + base + (size_t)(db0 + rd) * 1024 + kb0 + ck0) = h;
    }
  } else {
    const int i = (bid - 8192) * 256 + t;
    s16x8 h, l;
    if (i < 4194304) {
      cvt8(Q + (size_t)i * 8, h, l);
      *(s16x8*)(Qhi + (size_t)i * 8) = h;
      *(s16x8*)(Qlo + (size_t)i * 8) = l;
    } else {
      int j = i - 4194304;
      if (j < 131072) {
        cvt8(W + (size_t)j * 8, h, l);
        *(s16x8*)(Whi + (size_t)j * 8) = h;
        *(s16x8*)(Wlo + (size_t)j * 8) = l;
      }
    }
  }
}

// ================= qf GEMM -> fragment-ordered output =========================
__global__ __launch_bounds__(256, 2) void k_qf2(const unsigned short* __restrict__ Qhi,
                                                const unsigned short* __restrict__ Qlo,
                                                const unsigned short* __restrict__ Whi,
                                                const unsigned short* __restrict__ Wlo,
                                                const float* __restrict__ bias,
                                                float* __restrict__ outp) {
  __shared__ __align__(16) unsigned short Ah[128 * 64], Al[128 * 64], Bh[128 * 64], Bl[128 * 64];
  const int t = threadIdx.x;
  const int i = blockIdx.x + blockIdx.y * 256;
  const int x = i & 7, j = i >> 3;
  const int n0 = (j & 7) * 128;
  const int m0 = (x * 32 + (j >> 3)) * 128;
  const int w = t >> 6, l = t & 63, wm = w >> 1, wn = w & 1, g = l >> 4, ln = l & 15;
  const int lrow = l >> 3, lc8 = (l & 7) * 8;
  const f32x4 fz = {0.f, 0.f, 0.f, 0.f};
  f32x4 acc[4][4];
#pragma unroll
  for (int a = 0; a < 4; a++)
#pragma unroll
    for (int bq = 0; bq < 4; bq++) acc[a][bq] = fz;
#pragma unroll 1
  for (int k0 = 0; k0 < 1024; k0 += 64) {
#pragma unroll
    for (int jj = 0; jj < 4; jj++) {
      const int ch = w * 4 + jj;
      const int row = ch * 8 + lrow;
      const int sc = lc8 ^ (lrow << 3);
      gld16(Qhi + (size_t)(m0 + row) * 1024 + k0 + sc, &Ah[ch * 512]);
      gld16(Qlo + (size_t)(m0 + row) * 1024 + k0 + sc, &Al[ch * 512]);
      gld16(Whi + (size_t)(n0 + row) * 1024 + k0 + sc, &Bh[ch * 512]);
      gld16(Wlo + (size_t)(n0 + row) * 1024 + k0 + sc, &Bl[ch * 512]);
    }
    __syncthreads();
#pragma unroll
    for (int ks = 0; ks < 2; ks++) {
      const int kc = ks * 32 + g * 8;
      s16x8 ah[4], al[4], bh[4], bl[4];
#pragma unroll
      for (int mf = 0; mf < 4; mf++) {
        const int row = wm * 64 + mf * 16 + ln;
        const int idx = row * 64 + (kc ^ ((row & 7) << 3));
        ah[mf] = *(const s16x8*)&Ah[idx];
        al[mf] = *(const s16x8*)&Al[idx];
      }
#pragma unroll
      for (int nf = 0; nf < 4; nf++) {
        const int row = wn * 64 + nf * 16 + ln;
        const int idx = row * 64 + (kc ^ ((row & 7) << 3));
        bh[nf] = *(const s16x8*)&Bh[idx];
        bl[nf] = *(const s16x8*)&Bl[idx];
      }
#pragma unroll
      for (int mf = 0; mf < 4; mf++)
#pragma unroll
        for (int nf = 0; nf < 4; nf++) {
          acc[mf][nf] = MFMA16(ah[mf], bh[nf], acc[mf][nf]);
          acc[mf][nf] = MFMA16(ah[mf], bl[nf], acc[mf][nf]);
          acc[mf][nf] = MFMA16(al[mf], bh[nf], acc[mf][nf]);
        }
    }
    __syncthreads();
  }
  unsigned short* qA = (unsigned short*)outp;
#pragma unroll
  for (int nf = 0; nf < 4; nf++) {
    const int c = n0 + wn * 64 + nf * 16 + ln;
    const float bv = bias[c];
    const int kchunk = c >> 5, lhib = ((c >> 3) & 3) << 4, jj = c & 7;
#pragma unroll
    for (int mf = 0; mf < 4; mf++)
#pragma unroll
      for (int r = 0; r < 4; r++) {
        const int R = m0 + wm * 64 + mf * 16 + g * 4 + r;
        float v = acc[mf][nf][r] + bv;
        v = v > 0.f ? v : 0.f;
        unsigned short h = f2bf(v);
        const size_t fo = (((size_t)(R >> 4) * 32 + kchunk) * 64 + ((R & 15) + lhib)) * 8 + jj;
        qA[fo] = h;
        qA[QA_LO + fo] = f2bf(v - bf2f(h));
      }
  }
}

// ================= S = qf @ K^T, 256x256, BK=64 (R9/R11 order) ================
__global__ __launch_bounds__(512, 1) void k_sgemm8(const unsigned short* __restrict__ Khi,
                                                   const unsigned short* __restrict__ Klo,
                                                   const unsigned short* __restrict__ qA,
                                                   float* __restrict__ Sf) {
  __shared__ __align__(16) unsigned short Bh[2][256 * 64], Bl[2][256 * 64];
  const int t = threadIdx.x;
  const int i = blockIdx.x;
  const int x = i & 7, jj = i >> 3;
  const int b = x * 4 + (jj >> 4);
  const int qt = (jj >> 2) & 3, nt = jj & 3;
  const int q0g = b * 1024 + qt * 256;
  const int k0g = nt * 256;
  const int w = t >> 6, l = t & 63, wm = w >> 2, wn = w & 3, g = l >> 4, ln = l & 15;
  const int lrow = l >> 3, lc8 = (l & 7) * 8, sc = lc8 ^ (lrow << 3);
  const size_t kbase = (size_t)b * 1024 * 1024;
  const int qb0 = (q0g >> 4) + wm * 8;
  const f32x4 fz = {0.f, 0.f, 0.f, 0.f};
  f32x4 acc[8][4];
#pragma unroll
  for (int a = 0; a < 8; a++)
#pragma unroll
    for (int bq = 0; bq < 4; bq++) acc[a][bq] = fz;

  auto stageB = [&](int buf, int dc) {
#pragma unroll
    for (int jj2 = 0; jj2 < 4; jj2++) {
      const int ch = w * 4 + jj2;
      const int row = ch * 8 + lrow;
      const size_t go = kbase + (size_t)(k0g + row) * 1024 + dc * 64 + sc;
      gld16(Khi + go, &Bh[buf][ch * 512]);
      gld16(Klo + go, &Bl[buf][ch * 512]);
    }
  };

  stageB(0, 0);
#pragma unroll 1
  for (int dc = 0; dc < 16; dc++) {
    const int cur = dc & 1;
    asm volatile("s_waitcnt vmcnt(0)" ::: "memory");
    __builtin_amdgcn_s_barrier();
    __builtin_amdgcn_sched_barrier(0);
#pragma unroll
    for (int ks = 0; ks < 2; ks++) {
      s16x8 ah[8], al[8];
#pragma unroll
      for (int mf = 0; mf < 8; mf++) {
        const size_t fo = (((size_t)(qb0 + mf) * 32 + dc * 2 + ks) * 64 + l) * 8;
        ah[mf] = *(const s16x8*)(qA + fo);
        al[mf] = *(const s16x8*)(qA + QA_LO + fo);
      }
      if (ks == 0 && dc < 15) stageB(cur ^ 1, dc + 1);
      const int kc = ks * 32 + g * 8;
      s16x8 bh[4], bl[4];
#pragma unroll
      for (int nf = 0; nf < 4; nf++) {
        const int row = wn * 64 + nf * 16 + ln;
        const int idx = row * 64 + (kc ^ ((row & 7) << 3));
        bh[nf] = *(const s16x8*)&Bh[cur][idx];
        bl[nf] = *(const s16x8*)&Bl[cur][idx];
      }
      __builtin_amdgcn_s_setprio(1);
#pragma unroll
      for (int mf = 0; mf < 8; mf++)
#pragma unroll
        for (int nf = 0; nf < 4; nf++) {
          acc[mf][nf] = MFMA16(ah[mf], bh[nf], acc[mf][nf]);
          acc[mf][nf] = MFMA16(ah[mf], bl[nf], acc[mf][nf]);
          acc[mf][nf] = MFMA16(al[mf], bh[nf], acc[mf][nf]);
        }
      __builtin_amdgcn_s_setprio(0);
    }
  }
  // epilogue: S as f32 (single plane)
#pragma unroll
  for (int mf = 0; mf < 8; mf++)
#pragma unroll
    for (int nf = 0; nf < 4; nf++) {
      const int colS = k0g + wn * 64 + nf * 16 + ln;
#pragma unroll
      for (int r = 0; r < 4; r++) {
        const int rowS = q0g + wm * 128 + mf * 16 + g * 4 + r;
        Sf[(size_t)rowS * 1024 + colS] = acc[mf][nf][r];
      }
    }
}

// ================= masked softmax, streaming (f32 input) ======================
__global__ __launch_bounds__(256) void k_softmax(const float* __restrict__ Sf,
                                                 const float* __restrict__ mask,
                                                 unsigned short* __restrict__ P) {
  __shared__ float red[2][4];
  const int row = blockIdx.x;
  const int b = row >> 10;
  const int t = threadIdx.x, w = t >> 6, l = t & 63;
  const size_t base = (size_t)row * 1024 + t * 4;
  const f32x4 sv = *(const f32x4*)(Sf + base);
  const f32x4 mk = *(const f32x4*)(mask + b * 1024 + t * 4);
  float s[4];
  bool um[4];
#pragma unroll
  for (int j = 0; j < 4; j++) {
    s[j] = sv[j];
    um[j] = mk[j] != 0.f;
  }
  float mx = -1e30f;
#pragma unroll
  for (int j = 0; j < 4; j++)
    if (um[j]) mx = fmaxf(mx, s[j]);
#pragma unroll
  for (int off = 1; off < 64; off <<= 1) mx = fmaxf(mx, __shfl_xor(mx, off));
  if (l == 0) red[0][w] = mx;
  __syncthreads();
  mx = fmaxf(fmaxf(red[0][0], red[0][1]), fmaxf(red[0][2], red[0][3]));
  float e[4];
  float sum = 0.f;
#pragma unroll
  for (int j = 0; j < 4; j++) {
    e[j] = um[j] ? __expf(s[j] - mx) : 0.f;
    sum += e[j];
  }
#pragma unroll
  for (int off = 1; off < 64; off <<= 1) sum += __shfl_xor(sum, off);
  if (l == 0) red[1][w] = sum;
  __syncthreads();
  const float rinv = 1.f / (red[1][0] + red[1][1] + red[1][2] + red[1][3]);
  s16x4 o;
#pragma unroll
  for (int j = 0; j < 4; j++) o[j] = (short)f2bf(e[j] * rinv);
  *(s16x4*)(P + base) = o;
}

// ================= O = attn @ K via KhiT ======================================
__global__ __launch_bounds__(512, 1) void k_pv2(const unsigned short* __restrict__ KhiT,
                                                const unsigned short* __restrict__ attnw,
                                                float* __restrict__ dout) {
  __shared__ __align__(16) unsigned short Pb[2][128 * 64];
  __shared__ __align__(16) unsigned short KTb[2][512 * 64];
  const int t = threadIdx.x;
  const int i = blockIdx.y * 8 + blockIdx.x;
  const int x = i & 7, jj = i >> 3;
  const int b = x * 4 + (jj >> 3), qt = jj & 7;
  const int q0 = qt * 128, d0 = blockIdx.z * 512;
  const int w = t >> 6, l = t & 63, wm = w >> 2, wd = w & 3, g = l >> 4, ln = l & 15;
  const int lrow = l >> 3, lc8 = (l & 7) * 8, sc = lc8 ^ (lrow << 3);
  const f32x4 fz = {0.f, 0.f, 0.f, 0.f};
  f32x4 acc[4][8];
#pragma unroll
  for (int a = 0; a < 4; a++)
#pragma unroll
    for (int bq = 0; bq < 8; bq++) acc[a][bq] = fz;
  const size_t kbase = (size_t)b * 1024 * 1024;

  auto stageP = [&](int buf, int k0) {
#pragma unroll
    for (int jj2 = 0; jj2 < 2; jj2++) {
      const int ch = w * 2 + jj2;
      const int row = ch * 8 + lrow;
      gld16(attnw + (size_t)(b * 1024 + q0 + row) * 1024 + k0 + sc, &Pb[buf][ch * 512]);
    }
  };
  auto stageKT = [&](int buf, int k0) {
#pragma unroll
    for (int jj2 = 0; jj2 < 8; jj2++) {
      const int ch = w * 8 + jj2;
      const int row = ch * 8 + lrow;
      gld16(KhiT + kbase + (size_t)(d0 + row) * 1024 + k0 + sc, &KTb[buf][ch * 512]);
    }
  };

  stageP(0, 0);
  stageKT(0, 0);
#pragma unroll 1
  for (int s = 0; s < 16; s++) {
    asm volatile("s_waitcnt vmcnt(0)" ::: "memory");
    __builtin_amdgcn_s_barrier();
    __builtin_amdgcn_sched_barrier(0);
    if (s < 15) {
      stageP((s + 1) & 1, (s + 1) * 64);
      stageKT((s + 1) & 1, (s + 1) * 64);
    }
    const int cur = s & 1;
    __builtin_amdgcn_s_setprio(1);
#pragma unroll
    for (int ks = 0; ks < 2; ks++) {
      const int kc = ks * 32 + g * 8;
      s16x8 a[4], bb[8];
#pragma unroll
      for (int mf = 0; mf < 4; mf++) {
        const int row = wm * 64 + mf * 16 + ln;
        a[mf] = *(const s16x8*)&Pb[cur][row * 64 + (kc ^ ((row & 7) << 3))];
      }
#pragma unroll
      for (int nf = 0; nf < 8; nf++) {
        const int row = wd * 128 + nf * 16 + ln;
        bb[nf] = *(const s16x8*)&KTb[cur][row * 64 + (kc ^ ((row & 7) << 3))];
      }
#pragma unroll
      for (int mf = 0; mf < 4; mf++)
#pragma unroll
        for (int nf = 0; nf < 8; nf++) acc[mf][nf] = MFMA16(a[mf], bb[nf], acc[mf][nf]);
    }
    __builtin_amdgcn_s_setprio(0);
  }
#pragma unroll
  for (int mf = 0; mf < 4; mf++)
#pragma unroll
    for (int nf = 0; nf < 8; nf++)
#pragma unroll
      for (int r = 0; r < 4; r++) {
        const int q = q0 + wm * 64 + mf * 16 + g * 4 + r;
        const int d = d0 + wd * 128 + nf * 16 + ln;
        dout[(size_t)(b * 1024 + q) * 1024 + d] = acc[mf][nf][r];
      }
}

// ================= Tier C: round-1 kernels (fallback, unchanged) =============
__global__ __launch_bounds__(256, 2) void k_qf(const float* __restrict__ Q,
                                               const float* __restrict__ W,
                                               const float* __restrict__ bias,
                                               float* __restrict__ qf) {
  __shared__ __align__(16) short Ah[128 * 64], Al[128 * 64], Bh[128 * 64], Bl[128 * 64];
  const int t = threadIdx.x;
  const int m0 = blockIdx.x * 128, n0 = blockIdx.y * 128;
  const int w = t >> 6, l = t & 63, wm = w >> 1, wn = w & 1, g = l >> 4, ln = l & 15;
  const f32x4 fz = {0.f, 0.f, 0.f, 0.f};
  f32x4 acc[4][4];
#pragma unroll
  for (int a = 0; a < 4; a++)
#pragma unroll
    for (int bq = 0; bq < 4; bq++) acc[a][bq] = fz;
  const int srow = t >> 1, scol = (t & 1) * 32;
#pragma unroll 1
  for (int k0 = 0; k0 < 1024; k0 += 64) {
    const float* sa = Q + (size_t)(m0 + srow) * 1024 + k0 + scol;
    const float* sb = W + (size_t)(n0 + srow) * 1024 + k0 + scol;
#pragma unroll
    for (int c = 0; c < 32; c += 8) {
      s16x8 h, lo;
      cvt8(sa + c, h, lo);
      int si = swz(srow, scol + c);
      *(s16x8*)&Ah[si] = h;
      *(s16x8*)&Al[si] = lo;
    }
#pragma unroll
    for (int c = 0; c < 32; c += 8) {
      s16x8 h, lo;
      cvt8(sb + c, h, lo);
      int si = swz(srow, scol + c);
      *(s16x8*)&Bh[si] = h;
      *(s16x8*)&Bl[si] = lo;
    }
    __syncthreads();
#pragma unroll
    for (int ks = 0; ks < 2; ks++) {
      const int kc = ks * 32 + g * 8;
      s16x8 ah[4], al[4], bh[4], bl[4];
#pragma unroll
      for (int mf = 0; mf < 4; mf++) {
        int si = swz(wm * 64 + mf * 16 + ln, kc);
        ah[mf] = *(s16x8*)&Ah[si];
        al[mf] = *(s16x8*)&Al[si];
      }
#pragma unroll
      for (int nf = 0; nf < 4; nf++) {
        int si = swz(wn * 64 + nf * 16 + ln, kc);
        bh[nf] = *(s16x8*)&Bh[si];
        bl[nf] = *(s16x8*)&Bl[si];
      }
#pragma unroll
      for (int mf = 0; mf < 4; mf++)
#pragma unroll
        for (int nf = 0; nf < 4; nf++) {
          acc[mf][nf] = MFMA16(ah[mf], bh[nf], acc[mf][nf]);
          acc[mf][nf] = MFMA16(ah[mf], bl[nf], acc[mf][nf]);
          acc[mf][nf] = MFMA16(al[mf], bh[nf], acc[mf][nf]);
        }
    }
    __syncthreads();
  }
#pragma unroll
  for (int nf = 0; nf < 4; nf++) {
    const int col = n0 + wn * 64 + nf * 16 + ln;
    const float bv = bias[col];
#pragma unroll
    for (int mf = 0; mf < 4; mf++)
#pragma unroll
      for (int r = 0; r < 4; r++) {
        const int row = m0 + wm * 64 + mf * 16 + g * 4 + r;
        float v = acc[mf][nf][r] + bv;
        qf[(size_t)row * 1024 + col] = v > 0.f ? v : 0.f;
      }
  }
}

__global__ __launch_bounds__(512, 2) void k_attn(const float* __restrict__ Key,
                                                 const float* __restrict__ mask,
                                                 float* __restrict__ dout) {
  __shared__ __align__(16) short qh[64 * 64], qlo[64 * 64], kh[128 * 64], klo[128 * 64];
  __shared__ float mask_s[1024];
  __shared__ float red[4][64];
  const int t = threadIdx.x;
  const int qt = blockIdx.x, b = blockIdx.y;
  const int q0 = qt * 64;
  const int w = t >> 6, l = t & 63, wm = w >> 2, wn = w & 3, g = l >> 4, ln = l & 15;
  for (int i = t; i < 1024; i += 512) mask_s[i] = mask[b * 1024 + i];
  const f32x4 fz = {0.f, 0.f, 0.f, 0.f};
  f32x4 acc[8][2][2];
#pragma unroll
  for (int kt = 0; kt < 8; kt++)
#pragma unroll
    for (int mf = 0; mf < 2; mf++)
#pragma unroll
      for (int nf = 0; nf < 2; nf++) acc[kt][mf][nf] = fz;
  const float* qfb = dout + (size_t)(b * 1024 + q0) * 1024;
  const float* kb = Key + (size_t)b * 1024 * 1024;
  const int qrow = t >> 3, qcol = (t & 7) * 8;
  const int krow = t >> 2, kcol0 = (t & 3) * 16;
#pragma unroll 1
  for (int dc = 0; dc < 16; dc++) {
    {
      s16x8 h, lo;
      cvt8(qfb + (size_t)qrow * 1024 + dc * 64 + qcol, h, lo);
      int si = swz(qrow, qcol);
      *(s16x8*)&qh[si] = h;
      *(s16x8*)&qlo[si] = lo;
    }
#pragma unroll
    for (int kt = 0; kt < 8; kt++) {
      {
        const float* s = kb + (size_t)(kt * 128 + krow) * 1024 + dc * 64 + kcol0;
        s16x8 h, lo;
        cvt8(s, h, lo);
        int si = swz(krow, kcol0);
        *(s16x8*)&kh[si] = h;
        *(s16x8*)&klo[si] = lo;
        cvt8(s + 8, h, lo);
        si = swz(krow, kcol0 + 8);
        *(s16x8*)&kh[si] = h;
        *(s16x8*)&klo[si] = lo;
      }
      __syncthreads();
#pragma unroll
      for (int ks = 0; ks < 2; ks++) {
        const int kc = ks * 32 + g * 8;
        s16x8 ah[2], al2[2], bh[2], bl[2];
#pragma unroll
        for (int mf = 0; mf < 2; mf++) {
          int si = swz(wm * 32 + mf * 16 + ln, kc);
          ah[mf] = *(s16x8*)&qh[si];
          al2[mf] = *(s16x8*)&qlo[si];
        }
#pragma unroll
        for (int nf = 0; nf < 2; nf++) {
          int si = swz(wn * 32 + nf * 16 + ln, kc);
          bh[nf] = *(s16x8*)&kh[si];
          bl[nf] = *(s16x8*)&klo[si];
        }
#pragma unroll
        for (int mf = 0; mf < 2; mf++)
#pragma unroll
          for (int nf = 0; nf < 2; nf++) {
            acc[kt][mf][nf] = MFMA16(ah[mf], bh[nf], acc[kt][mf][nf]);
            acc[kt][mf][nf] = MFMA16(ah[mf], bl[nf], acc[kt][mf][nf]);
            acc[kt][mf][nf] = MFMA16(al2[mf], bh[nf], acc[kt][mf][nf]);
          }
      }
      __syncthreads();
    }
  }
  float rmax[2][4];
#pragma unroll
  for (int mf = 0; mf < 2; mf++)
#pragma unroll
    for (int r = 0; r < 4; r++) rmax[mf][r] = -1e30f;
#pragma unroll
  for (int kt = 0; kt < 8; kt++)
#pragma unroll
    for (int nf = 0; nf < 2; nf++) {
      const int k = kt * 128 + wn * 32 + nf * 16 + ln;
      const bool mk = mask_s[k] != 0.f;
#pragma unroll
      for (int mf = 0; mf < 2; mf++)
#pragma unroll
        for (int r = 0; r < 4; r++)
          if (mk) rmax[mf][r] = fmaxf(rmax[mf][r], acc[kt][mf][nf][r]);
    }
#pragma unroll
  for (int off = 1; off < 16; off <<= 1)
#pragma unroll
    for (int mf = 0; mf < 2; mf++)
#pragma unroll
      for (int r = 0; r < 4; r++) rmax[mf][r] = fmaxf(rmax[mf][r], __shfl_xor(rmax[mf][r], off));
  if (ln == 0) {
#pragma unroll
    for (int mf = 0; mf < 2; mf++)
#pragma unroll
      for (int r = 0; r < 4; r++) red[wn][wm * 32 + mf * 16 + g * 4 + r] = rmax[mf][r];
  }
  __syncthreads();
#pragma unroll
  for (int mf = 0; mf < 2; mf++)
#pragma unroll
    for (int r = 0; r < 4; r++) {
      const int row = wm * 32 + mf * 16 + g * 4 + r;
      rmax[mf][r] = fmaxf(fmaxf(red[0][row], red[1][row]), fmaxf(red[2][row], red[3][row]));
    }
  __syncthreads();
  float rsum[2][4];
#pragma unroll
  for (int mf = 0; mf < 2; mf++)
#pragma unroll
    for (int r = 0; r < 4; r++) rsum[mf][r] = 0.f;
#pragma unroll
  for (int kt = 0; kt < 8; kt++)
#pragma unroll
    for (int nf = 0; nf < 2; nf++) {
      const int k = kt * 128 + wn * 32 + nf * 16 + ln;
      const bool mk = mask_s[k] != 0.f;
#pragma unroll
      for (int mf = 0; mf < 2; mf++)
#pragma unroll
        for (int r = 0; r < 4; r++)
          if (mk) rsum[mf][r] += __expf(acc[kt][mf][nf][r] - rmax[mf][r]);
    }
#pragma unroll
  for (int off = 1; off < 16; off <<= 1)
#pragma unroll
    for (int mf = 0; mf < 2; mf++)
#pragma unroll
      for (int r = 0; r < 4; r++) rsum[mf][r] += __shfl_xor(rsum[mf][r], off);
  if (ln == 0) {
#pragma unroll
    for (int mf = 0; mf < 2; mf++)
#pragma unroll
      for (int r = 0; r < 4; r++) red[wn][wm * 32 + mf * 16 + g * 4 + r] = rsum[mf][r];
  }
  __syncthreads();
  float rinv[2][4];
#pragma unroll
  for (int mf = 0; mf < 2; mf++)
#pragma unroll
    for (int r = 0; r < 4; r++) {
      const int row = wm * 32 + mf * 16 + g * 4 + r;
      rinv[mf][r] = 1.f / (red[0][row] + red[1][row] + red[2][row] + red[3][row]);
    }
  char* oc = (char*)dout;
#pragma unroll
  for (int kt = 0; kt < 8; kt++)
#pragma unroll
    for (int nf = 0; nf < 2; nf++) {
      const int k = kt * 128 + wn * 32 + nf * 16 + ln;
      const bool mk = mask_s[k] != 0.f;
#pragma unroll
      for (int mf = 0; mf < 2; mf++)
#pragma unroll
        for (int r = 0; r < 4; r++) {
          const int q = q0 + wm * 32 + mf * 16 + g * 4 + r;
          float p = mk ? __expf(acc[kt][mf][nf][r] - rmax[mf][r]) * rinv[mf][r] : 0.f;
          *(unsigned short*)(oc + (size_t)(b * 1024 + q) * 4096 + 2048 + k * 2) = f2bf(p);
        }
    }
}

__global__ __launch_bounds__(512, 2) void k_pv(const float* __restrict__ Key,
                                               float* __restrict__ dout, const int dh) {
  __shared__ __align__(16) short P[128 * 64];
  __shared__ __align__(16) short KT[512 * 64];
  const int t = threadIdx.x;
  const int qt = blockIdx.x, b = blockIdx.y;
  const int q0 = qt * 128, d0 = dh * 512;
  const int w = t >> 6, l = t & 63, wm = w >> 2, wd = w & 3, g = l >> 4, ln = l & 15;
  const f32x4 fz = {0.f, 0.f, 0.f, 0.f};
  f32x4 acc[4][8];
#pragma unroll
  for (int a = 0; a < 4; a++)
#pragma unroll
    for (int bq = 0; bq < 8; bq++) acc[a][bq] = fz;
  const char* ab = (const char*)dout;
  const int prow = t >> 2, pc0 = (t & 3) * 16;
#pragma unroll 1
  for (int k0 = 0; k0 < 1024; k0 += 64) {
    {
      const unsigned short* s =
          (const unsigned short*)(ab + (size_t)(b * 1024 + q0 + prow) * 4096 + 2048) + k0 + pc0;
      s16x8 p0 = *(const s16x8*)s, p1 = *(const s16x8*)(s + 8);
      *(s16x8*)&P[swz(prow, pc0)] = p0;
      *(s16x8*)&P[swz(prow, pc0 + 8)] = p1;
    }
    {
      const float* ksrc = Key + (size_t)b * 1024 * 1024 + (size_t)k0 * 1024 + d0 + t;
#pragma unroll
      for (int kg = 0; kg < 8; kg++) {
        s16x8 h;
#pragma unroll
        for (int jx = 0; jx < 8; jx++) h[jx] = (short)f2bf(ksrc[(size_t)(kg * 8 + jx) * 1024]);
        *(s16x8*)&KT[swz(t, kg * 8)] = h;
      }
    }
    __syncthreads();
#pragma unroll
    for (int ks = 0; ks < 2; ks++) {
      const int kc = ks * 32 + g * 8;
      s16x8 a[4], bb[8];
#pragma unroll
      for (int mf = 0; mf < 4; mf++) a[mf] = *(s16x8*)&P[swz(wm * 64 + mf * 16 + ln, kc)];
#pragma unroll
      for (int nf = 0; nf < 8; nf++) bb[nf] = *(s16x8*)&KT[swz(wd * 128 + nf * 16 + ln, kc)];
#pragma unroll
      for (int mf = 0; mf < 4; mf++)
#pragma unroll
        for (int nf = 0; nf < 8; nf++) acc[mf][nf] = MFMA16(a[mf], bb[nf], acc[mf][nf]);
    }
    __syncthreads();
  }
#pragma unroll
  for (int mf = 0; mf < 4; mf++)
#pragma unroll
    for (int nf = 0; nf < 8; nf++)
#pragma unroll
      for (int r = 0; r < 4; r++) {
        const int q = q0 + wm * 64 + mf * 16 + g * 4 + r;
        const int d = d0 + wd * 128 + nf * 16 + ln;
        dout[(size_t)(b * 1024 + q) * 1024 + d] = acc[mf][nf][r];
      }
}

extern "C" void kernel_launch(void* const* d_in, const int* in_sizes, int n_in,
                              void* d_out, int out_size, void* d_ws, size_t ws_size,
                              hipStream_t stream) {
  const float* Q = (const float*)d_in[0];
  const float* K = (const float*)d_in[1];
  const float* M = (const float*)d_in[2];
  const float* W = (const float*)d_in[3];
  const float* bias = (const float*)d_in[4];
  float* out = (float*)d_out;
  char* wsb = (char*)d_ws;
  (void)in_sizes; (void)n_in; (void)out_size;

  if (ws_size >= WS_TIER_A) {
    unsigned short* Khi = (unsigned short*)(wsb + OFF_KHI);
    unsigned short* Klo = (unsigned short*)(wsb + OFF_KLO);
    unsigned short* KhiT = (unsigned short*)(wsb + OFF_KHIT);
    unsigned short* Qhi = (unsigned short*)(wsb + OFF_QHI);
    unsigned short* Qlo = (unsigned short*)(wsb + OFF_QLO);
    unsigned short* Whi = (unsigned short*)(wsb + OFF_WHI);
    unsigned short* Wlo = (unsigned short*)(wsb + OFF_WLO);
    float* Sf = (float*)(wsb + OFF_QHI);  // 128MB, Q planes dead after qf2
    unsigned short* Pw = Klo;             // dead after sgemm8
    k_cvt_all<<<25088, 256, 0, stream>>>(K, Khi, Klo, KhiT, Q, Qhi, Qlo, W, Whi, Wlo);
    k_qf2<<<dim3(256, 8), 256, 0, stream>>>(Qhi, Qlo, Whi, Wlo, bias, out);
    k_sgemm8<<<512, 512, 0, stream>>>(Khi, Klo, (const unsigned short*)out, Sf);
    k_softmax<<<32768, 256, 0, stream>>>(Sf, M, Pw);
    k_pv2<<<dim3(8, 32, 2), 512, 0, stream>>>(KhiT, Pw, out);
  } else {
    k_qf<<<dim3(256, 8), 256, 0, stream>>>(Q, W, bias, out);
    k_attn<<<dim3(16, 32), 512, 0, stream>>>(K, M, out);
    k_pv<<<dim3(8, 32), 512, 0, stream>>>(K, out, 0);
    k_pv<<<dim3(8, 32), 512, 0, stream>>>(K, out, 1);
  }
}

// Round 16
// 684.174 us; speedup vs baseline: 1.0439x; 1.0030x over previous
//
#include <hip/hip_runtime.h>
#include <hip/hip_bf16.h>

// WordSentAtt: qf = relu(Q@W^T + b); S = qf@K^T (masked); attn = softmax; O = attn@K
// B=32, Lq=Lk=D=1024, f32 in/out. Split-bf16 (hi/lo) MFMA for qf and S.
// R16 = R13 (best: 686us) + heterogeneous launch: K-conversion (memory-bound,
//   ~55us, independent of qf) merged into qf2's launch as extra blocks ->
//   overlaps with qf2's compute (qf2 uses only 7% HBM). Q/W-cvt stays a
//   prior standalone launch (same-launch ordering undefined).
//   Structure ceiling note: both GEMMs measured ~905 TF = documented 2-barrier
//   ceiling (MfmaUtil 37-40%); register budget (128 acc + ~120 VGPR) pins
//   occupancy at 1 block/CU for sgemm8 (R12 falsified the LDS theory).

typedef __attribute__((ext_vector_type(4))) float f32x4;
typedef __attribute__((ext_vector_type(8))) short s16x8;
typedef __attribute__((ext_vector_type(4))) short s16x4;

#define MFMA16(a, b, c) __builtin_amdgcn_mfma_f32_16x16x32_bf16((a), (b), (c), 0, 0, 0)

__device__ __forceinline__ unsigned short f2bf(float x) {
  unsigned u = __builtin_bit_cast(unsigned, x);
  return (unsigned short)((u + 0x7FFFu + ((u >> 16) & 1u)) >> 16);
}
__device__ __forceinline__ float bf2f(unsigned short h) {
  return __builtin_bit_cast(float, ((unsigned)h) << 16);
}
__device__ __forceinline__ int swz(int row, int col) {
  return (row * 64 + col) ^ ((row & 7) << 3);
}
__device__ __forceinline__ void cvt8(const float* __restrict__ s, s16x8& h8, s16x8& l8) {
  f32x4 a = *(const f32x4*)s;
  f32x4 b = *(const f32x4*)(s + 4);
#pragma unroll
  for (int i = 0; i < 8; i++) {
    float v = (i < 4) ? a[i] : b[i - 4];
    unsigned short hu = f2bf(v);
    unsigned short lu = f2bf(v - bf2f(hu));
    h8[i] = (short)hu;
    l8[i] = (short)lu;
  }
}
__device__ __forceinline__ void gld16(const void* g, void* lds) {
  __builtin_amdgcn_global_load_lds((const __attribute__((address_space(1))) unsigned int*)g,
                                   (__attribute__((address_space(3))) unsigned int*)lds, 16, 0, 0);
}

// ws layout (bytes)
#define OFF_KHI 0ULL
#define OFF_KLO 67108864ULL   // dead after sgemm8 -> P bf16
#define OFF_KHIT 134217728ULL
#define OFF_QHI 201326592ULL  // Qhi; Q planes dead after qf2 -> S f32 (128MB)
#define OFF_QLO 268435456ULL  // Qlo
#define OFF_WHI 335544320ULL
#define OFF_WLO 337641472ULL
#define WS_TIER_A 339738624ULL
#define QA_LO 33554432ULL  // u16 offset of lo plane inside d_out frag layout

// ================= launch 1: Q/W pre-convert =================
__global__ __launch_bounds__(256) void k_cvt_qw(const float* __restrict__ Q,
                                                unsigned short* __restrict__ Qhi,
                                                unsigned short* __restrict__ Qlo,
                                                const float* __restrict__ W,
                                                unsigned short* __restrict__ Whi,
                                                unsigned short* __restrict__ Wlo) {
  int i = blockIdx.x * 256 + threadIdx.x;
  s16x8 h, l;
  if (i < 4194304) {
    cvt8(Q + (size_t)i * 8, h, l);
    *(s16x8*)(Qhi + (size_t)i * 8) = h;
    *(s16x8*)(Qlo + (size_t)i * 8) = l;
  } else {
    int j = i - 4194304;
    if (j < 131072) {
      cvt8(W + (size_t)j * 8, h, l);
      *(s16x8*)(Whi + (size_t)j * 8) = h;
      *(s16x8*)(Wlo + (size_t)j * 8) = l;
    }
  }
}

// ================= launch 2: qf GEMM + K-conversion (heterogeneous) ===========
// blocks [0,2048): qf2 body (128x128 tile, frag-ordered output to d_out).
// blocks [2048,10240): K[b][k][d] f32 -> Khi/Klo + KhiT (LDS transpose).
__global__ __launch_bounds__(256, 2) void k_qf2k(const unsigned short* __restrict__ Qhi,
                                                 const unsigned short* __restrict__ Qlo,
                                                 const unsigned short* __restrict__ Whi,
                                                 const unsigned short* __restrict__ Wlo,
                                                 const float* __restrict__ bias,
                                                 float* __restrict__ outp,
                                                 const float* __restrict__ K,
                                                 unsigned short* __restrict__ Khi,
                                                 unsigned short* __restrict__ Klo,
                                                 unsigned short* __restrict__ KhiT) {
  __shared__ __align__(16) char smem[65536];
  const int bid = blockIdx.x;
  const int t = threadIdx.x;

  if (bid >= 2048) {  // ---- K-conversion body ----
    unsigned* T = (unsigned*)smem;  // 64*65*4 = 16640 B
    const int kb = bid - 2048;
    const int db0 = (kb & 15) * 64, kb0 = ((kb >> 4) & 15) * 64, b = kb >> 8;
    const size_t base = (size_t)b * 1024 * 1024;
#pragma unroll
    for (int i = 0; i < 2; i++) {
      const int r = (t >> 3) + i * 32, c0 = (t & 7) * 8;
      s16x8 h, l;
      cvt8(K + base + (size_t)(kb0 + r) * 1024 + db0 + c0, h, l);
      *(s16x8*)(Khi + base + (size_t)(kb0 + r) * 1024 + db0 + c0) = h;
      *(s16x8*)(Klo + base + (size_t)(kb0 + r) * 1024 + db0 + c0) = l;
#pragma unroll
      for (int j = 0; j < 8; j++)
        T[r * 65 + c0 + j] = ((unsigned)(unsigned short)h[j] << 16) | (unsigned short)l[j];
    }
    __syncthreads();
#pragma unroll
    for (int i = 0; i < 2; i++) {
      const int rd = (t >> 3) + i * 32, ck0 = (t & 7) * 8;
      s16x8 h;
#pragma unroll
      for (int j = 0; j < 8; j++) h[j] = (short)(unsigned short)(T[(ck0 + j) * 65 + rd] >> 16);
      *(s16x8*)(KhiT + base + (size_t)(db0 + rd) * 1024 + kb0 + ck0) = h;
    }
    return;
  }

  // ---- qf2 body ----
  unsigned short* Ah = (unsigned short*)smem;
  unsigned short* Al = Ah + 128 * 64;
  unsigned short* Bh = Al + 128 * 64;
  unsigned short* Bl = Bh + 128 * 64;
  const int i = bid;
  const int x = i & 7, j = i >> 3;
  const int n0 = (j & 7) * 128;
  const int m0 = (x * 32 + (j >> 3)) * 128;
  const int w = t >> 6, l = t & 63, wm = w >> 1, wn = w & 1, g = l >> 4, ln = l & 15;
  const int lrow = l >> 3, lc8 = (l & 7) * 8;
  const f32x4 fz = {0.f, 0.f, 0.f, 0.f};
  f32x4 acc[4][4];
#pragma unroll
  for (int a = 0; a < 4; a++)
#pragma unroll
    for (int bq = 0; bq < 4; bq++) acc[a][bq] = fz;
#pragma unroll 1
  for (int k0 = 0; k0 < 1024; k0 += 64) {
#pragma unroll
    for (int jj = 0; jj < 4; jj++) {
      const int ch = w * 4 + jj;
      const int row = ch * 8 + lrow;
      const int sc = lc8 ^ (lrow << 3);
      gld16(Qhi + (size_t)(m0 + row) * 1024 + k0 + sc, &Ah[ch * 512]);
      gld16(Qlo + (size_t)(m0 + row) * 1024 + k0 + sc, &Al[ch * 512]);
      gld16(Whi + (size_t)(n0 + row) * 1024 + k0 + sc, &Bh[ch * 512]);
      gld16(Wlo + (size_t)(n0 + row) * 1024 + k0 + sc, &Bl[ch * 512]);
    }
    __syncthreads();
#pragma unroll
    for (int ks = 0; ks < 2; ks++) {
      const int kc = ks * 32 + g * 8;
      s16x8 ah[4], al[4], bh[4], bl[4];
#pragma unroll
      for (int mf = 0; mf < 4; mf++) {
        const int row = wm * 64 + mf * 16 + ln;
        const int idx = row * 64 + (kc ^ ((row & 7) << 3));
        ah[mf] = *(const s16x8*)&Ah[idx];
        al[mf] = *(const s16x8*)&Al[idx];
      }
#pragma unroll
      for (int nf = 0; nf < 4; nf++) {
        const int row = wn * 64 + nf * 16 + ln;
        const int idx = row * 64 + (kc ^ ((row & 7) << 3));
        bh[nf] = *(const s16x8*)&Bh[idx];
        bl[nf] = *(const s16x8*)&Bl[idx];
      }
#pragma unroll
      for (int mf = 0; mf < 4; mf++)
#pragma unroll
        for (int nf = 0; nf < 4; nf++) {
          acc[mf][nf] = MFMA16(ah[mf], bh[nf], acc[mf][nf]);
          acc[mf][nf] = MFMA16(ah[mf], bl[nf], acc[mf][nf]);
          acc[mf][nf] = MFMA16(al[mf], bh[nf], acc[mf][nf]);
        }
    }
    __syncthreads();
  }
  unsigned short* qA = (unsigned short*)outp;
#pragma unroll
  for (int nf = 0; nf < 4; nf++) {
    const int c = n0 + wn * 64 + nf * 16 + ln;
    const float bv = bias[c];
    const int kchunk = c >> 5, lhib = ((c >> 3) & 3) << 4, jj = c & 7;
#pragma unroll
    for (int mf = 0; mf < 4; mf++)
#pragma unroll
      for (int r = 0; r < 4; r++) {
        const int R = m0 + wm * 64 + mf * 16 + g * 4 + r;
        float v = acc[mf][nf][r] + bv;
        v = v > 0.f ? v : 0.f;
        unsigned short h = f2bf(v);
        const size_t fo = (((size_t)(R >> 4) * 32 + kchunk) * 64 + ((R & 15) + lhib)) * 8 + jj;
        qA[fo] = h;
        qA[QA_LO + fo] = f2bf(v - bf2f(h));
      }
  }
}

// ================= S = qf @ K^T, 256x256, BK=64 (R9/R11 order) ================
__global__ __launch_bounds__(512, 1) void k_sgemm8(const unsigned short* __restrict__ Khi,
                                                   const unsigned short* __restrict__ Klo,
                                                   const unsigned short* __restrict__ qA,
                                                   float* __restrict__ Sf) {
  __shared__ __align__(16) unsigned short Bh[2][256 * 64], Bl[2][256 * 64];
  const int t = threadIdx.x;
  const int i = blockIdx.x;
  const int x = i & 7, jj = i >> 3;
  const int b = x * 4 + (jj >> 4);
  const int qt = (jj >> 2) & 3, nt = jj & 3;
  const int q0g = b * 1024 + qt * 256;
  const int k0g = nt * 256;
  const int w = t >> 6, l = t & 63, wm = w >> 2, wn = w & 3, g = l >> 4, ln = l & 15;
  const int lrow = l >> 3, lc8 = (l & 7) * 8, sc = lc8 ^ (lrow << 3);
  const size_t kbase = (size_t)b * 1024 * 1024;
  const int qb0 = (q0g >> 4) + wm * 8;
  const f32x4 fz = {0.f, 0.f, 0.f, 0.f};
  f32x4 acc[8][4];
#pragma unroll
  for (int a = 0; a < 8; a++)
#pragma unroll
    for (int bq = 0; bq < 4; bq++) acc[a][bq] = fz;

  auto stageB = [&](int buf, int dc) {
#pragma unroll
    for (int jj2 = 0; jj2 < 4; jj2++) {
      const int ch = w * 4 + jj2;
      const int row = ch * 8 + lrow;
      const size_t go = kbase + (size_t)(k0g + row) * 1024 + dc * 64 + sc;
      gld16(Khi + go, &Bh[buf][ch * 512]);
      gld16(Klo + go, &Bl[buf][ch * 512]);
    }
  };

  stageB(0, 0);
#pragma unroll 1
  for (int dc = 0; dc < 16; dc++) {
    const int cur = dc & 1;
    asm volatile("s_waitcnt vmcnt(0)" ::: "memory");
    __builtin_amdgcn_s_barrier();
    __builtin_amdgcn_sched_barrier(0);
#pragma unroll
    for (int ks = 0; ks < 2; ks++) {
      s16x8 ah[8], al[8];
#pragma unroll
      for (int mf = 0; mf < 8; mf++) {
        const size_t fo = (((size_t)(qb0 + mf) * 32 + dc * 2 + ks) * 64 + l) * 8;
        ah[mf] = *(const s16x8*)(qA + fo);
        al[mf] = *(const s16x8*)(qA + QA_LO + fo);
      }
      if (ks == 0 && dc < 15) stageB(cur ^ 1, dc + 1);
      const int kc = ks * 32 + g * 8;
      s16x8 bh[4], bl[4];
#pragma unroll
      for (int nf = 0; nf < 4; nf++) {
        const int row = wn * 64 + nf * 16 + ln;
        const int idx = row * 64 + (kc ^ ((row & 7) << 3));
        bh[nf] = *(const s16x8*)&Bh[cur][idx];
        bl[nf] = *(const s16x8*)&Bl[cur][idx];
      }
      __builtin_amdgcn_s_setprio(1);
#pragma unroll
      for (int mf = 0; mf < 8; mf++)
#pragma unroll
        for (int nf = 0; nf < 4; nf++) {
          acc[mf][nf] = MFMA16(ah[mf], bh[nf], acc[mf][nf]);
          acc[mf][nf] = MFMA16(ah[mf], bl[nf], acc[mf][nf]);
          acc[mf][nf] = MFMA16(al[mf], bh[nf], acc[mf][nf]);
        }
      __builtin_amdgcn_s_setprio(0);
    }
  }
#pragma unroll
  for (int mf = 0; mf < 8; mf++)
#pragma unroll
    for (int nf = 0; nf < 4; nf++) {
      const int colS = k0g + wn * 64 + nf * 16 + ln;
#pragma unroll
      for (int r = 0; r < 4; r++) {
        const int rowS = q0g + wm * 128 + mf * 16 + g * 4 + r;
        Sf[(size_t)rowS * 1024 + colS] = acc[mf][nf][r];
      }
    }
}

// ================= masked softmax, streaming (f32 input) ======================
__global__ __launch_bounds__(256) void k_softmax(const float* __restrict__ Sf,
                                                 const float* __restrict__ mask,
                                                 unsigned short* __restrict__ P) {
  __shared__ float red[2][4];
  const int row = blockIdx.x;
  const int b = row >> 10;
  const int t = threadIdx.x, w = t >> 6, l = t & 63;
  const size_t base = (size_t)row * 1024 + t * 4;
  const f32x4 sv = *(const f32x4*)(Sf + base);
  const f32x4 mk = *(const f32x4*)(mask + b * 1024 + t * 4);
  float s[4];
  bool um[4];
#pragma unroll
  for (int j = 0; j < 4; j++) {
    s[j] = sv[j];
    um[j] = mk[j] != 0.f;
  }
  float mx = -1e30f;
#pragma unroll
  for (int j = 0; j < 4; j++)
    if (um[j]) mx = fmaxf(mx, s[j]);
#pragma unroll
  for (int off = 1; off < 64; off <<= 1) mx = fmaxf(mx, __shfl_xor(mx, off));
  if (l == 0) red[0][w] = mx;
  __syncthreads();
  mx = fmaxf(fmaxf(red[0][0], red[0][1]), fmaxf(red[0][2], red[0][3]));
  float e[4];
  float sum = 0.f;
#pragma unroll
  for (int j = 0; j < 4; j++) {
    e[j] = um[j] ? __expf(s[j] - mx) : 0.f;
    sum += e[j];
  }
#pragma unroll
  for (int off = 1; off < 64; off <<= 1) sum += __shfl_xor(sum, off);
  if (l == 0) red[1][w] = sum;
  __syncthreads();
  const float rinv = 1.f / (red[1][0] + red[1][1] + red[1][2] + red[1][3]);
  s16x4 o;
#pragma unroll
  for (int j = 0; j < 4; j++) o[j] = (short)f2bf(e[j] * rinv);
  *(s16x4*)(P + base) = o;
}

// ================= O = attn @ K via KhiT ======================================
__global__ __launch_bounds__(512, 1) void k_pv2(const unsigned short* __restrict__ KhiT,
                                                const unsigned short* __restrict__ attnw,
                                                float* __restrict__ dout) {
  __shared__ __align__(16) unsigned short Pb[2][128 * 64];
  __shared__ __align__(16) unsigned short KTb[2][512 * 64];
  const int t = threadIdx.x;
  const int i = blockIdx.y * 8 + blockIdx.x;
  const int x = i & 7, jj = i >> 3;
  const int b = x * 4 + (jj >> 3), qt = jj & 7;
  const int q0 = qt * 128, d0 = blockIdx.z * 512;
  const int w = t >> 6, l = t & 63, wm = w >> 2, wd = w & 3, g = l >> 4, ln = l & 15;
  const int lrow = l >> 3, lc8 = (l & 7) * 8, sc = lc8 ^ (lrow << 3);
  const f32x4 fz = {0.f, 0.f, 0.f, 0.f};
  f32x4 acc[4][8];
#pragma unroll
  for (int a = 0; a < 4; a++)
#pragma unroll
    for (int bq = 0; bq < 8; bq++) acc[a][bq] = fz;
  const size_t kbase = (size_t)b * 1024 * 1024;

  auto stageP = [&](int buf, int k0) {
#pragma unroll
    for (int jj2 = 0; jj2 < 2; jj2++) {
      const int ch = w * 2 + jj2;
      const int row = ch * 8 + lrow;
      gld16(attnw + (size_t)(b * 1024 + q0 + row) * 1024 + k0 + sc, &Pb[buf][ch * 512]);
    }
  };
  auto stageKT = [&](int buf, int k0) {
#pragma unroll
    for (int jj2 = 0; jj2 < 8; jj2++) {
      const int ch = w * 8 + jj2;
      const int row = ch * 8 + lrow;
      gld16(KhiT + kbase + (size_t)(d0 + row) * 1024 + k0 + sc, &KTb[buf][ch * 512]);
    }
  };

  stageP(0, 0);
  stageKT(0, 0);
#pragma unroll 1
  for (int s = 0; s < 16; s++) {
    asm volatile("s_waitcnt vmcnt(0)" ::: "memory");
    __builtin_amdgcn_s_barrier();
    __builtin_amdgcn_sched_barrier(0);
    if (s < 15) {
      stageP((s + 1) & 1, (s + 1) * 64);
      stageKT((s + 1) & 1, (s + 1) * 64);
    }
    const int cur = s & 1;
    __builtin_amdgcn_s_setprio(1);
#pragma unroll
    for (int ks = 0; ks < 2; ks++) {
      const int kc = ks * 32 + g * 8;
      s16x8 a[4], bb[8];
#pragma unroll
      for (int mf = 0; mf < 4; mf++) {
        const int row = wm * 64 + mf * 16 + ln;
        a[mf] = *(const s16x8*)&Pb[cur][row * 64 + (kc ^ ((row & 7) << 3))];
      }
#pragma unroll
      for (int nf = 0; nf < 8; nf++) {
        const int row = wd * 128 + nf * 16 + ln;
        bb[nf] = *(const s16x8*)&KTb[cur][row * 64 + (kc ^ ((row & 7) << 3))];
      }
#pragma unroll
      for (int mf = 0; mf < 4; mf++)
#pragma unroll
        for (int nf = 0; nf < 8; nf++) acc[mf][nf] = MFMA16(a[mf], bb[nf], acc[mf][nf]);
    }
    __builtin_amdgcn_s_setprio(0);
  }
#pragma unroll
  for (int mf = 0; mf < 4; mf++)
#pragma unroll
    for (int nf = 0; nf < 8; nf++)
#pragma unroll
      for (int r = 0; r < 4; r++) {
        const int q = q0 + wm * 64 + mf * 16 + g * 4 + r;
        const int d = d0 + wd * 128 + nf * 16 + ln;
        dout[(size_t)(b * 1024 + q) * 1024 + d] = acc[mf][nf][r];
      }
}

// ================= Tier C: round-1 kernels (fallback, unchanged) =============
__global__ __launch_bounds__(256, 2) void k_qf(const float* __restrict__ Q,
                                               const float* __restrict__ W,
                                               const float* __restrict__ bias,
                                               float* __restrict__ qf) {
  __shared__ __align__(16) short Ah[128 * 64], Al[128 * 64], Bh[128 * 64], Bl[128 * 64];
  const int t = threadIdx.x;
  const int m0 = blockIdx.x * 128, n0 = blockIdx.y * 128;
  const int w = t >> 6, l = t & 63, wm = w >> 1, wn = w & 1, g = l >> 4, ln = l & 15;
  const f32x4 fz = {0.f, 0.f, 0.f, 0.f};
  f32x4 acc[4][4];
#pragma unroll
  for (int a = 0; a < 4; a++)
#pragma unroll
    for (int bq = 0; bq < 4; bq++) acc[a][bq] = fz;
  const int srow = t >> 1, scol = (t & 1) * 32;
#pragma unroll 1
  for (int k0 = 0; k0 < 1024; k0 += 64) {
    const float* sa = Q + (size_t)(m0 + srow) * 1024 + k0 + scol;
    const float* sb = W + (size_t)(n0 + srow) * 1024 + k0 + scol;
#pragma unroll
    for (int c = 0; c < 32; c += 8) {
      s16x8 h, lo;
      cvt8(sa + c, h, lo);
      int si = swz(srow, scol + c);
      *(s16x8*)&Ah[si] = h;
      *(s16x8*)&Al[si] = lo;
    }
#pragma unroll
    for (int c = 0; c < 32; c += 8) {
      s16x8 h, lo;
      cvt8(sb + c, h, lo);
      int si = swz(srow, scol + c);
      *(s16x8*)&Bh[si] = h;
      *(s16x8*)&Bl[si] = lo;
    }
    __syncthreads();
#pragma unroll
    for (int ks = 0; ks < 2; ks++) {
      const int kc = ks * 32 + g * 8;
      s16x8 ah[4], al[4], bh[4], bl[4];
#pragma unroll
      for (int mf = 0; mf < 4; mf++) {
        int si = swz(wm * 64 + mf * 16 + ln, kc);
        ah[mf] = *(s16x8*)&Ah[si];
        al[mf] = *(s16x8*)&Al[si];
      }
#pragma unroll
      for (int nf = 0; nf < 4; nf++) {
        int si = swz(wn * 64 + nf * 16 + ln, kc);
        bh[nf] = *(s16x8*)&Bh[si];
        bl[nf] = *(s16x8*)&Bl[si];
      }
#pragma unroll
      for (int mf = 0; mf < 4; mf++)
#pragma unroll
        for (int nf = 0; nf < 4; nf++) {
          acc[mf][nf] = MFMA16(ah[mf], bh[nf], acc[mf][nf]);
          acc[mf][nf] = MFMA16(ah[mf], bl[nf], acc[mf][nf]);
          acc[mf][nf] = MFMA16(al[mf], bh[nf], acc[mf][nf]);
        }
    }
    __syncthreads();
  }
#pragma unroll
  for (int nf = 0; nf < 4; nf++) {
    const int col = n0 + wn * 64 + nf * 16 + ln;
    const float bv = bias[col];
#pragma unroll
    for (int mf = 0; mf < 4; mf++)
#pragma unroll
      for (int r = 0; r < 4; r++) {
        const int row = m0 + wm * 64 + mf * 16 + g * 4 + r;
        float v = acc[mf][nf][r] + bv;
        qf[(size_t)row * 1024 + col] = v > 0.f ? v : 0.f;
      }
  }
}

__global__ __launch_bounds__(512, 2) void k_attn(const float* __restrict__ Key,
                                                 const float* __restrict__ mask,
                                                 float* __restrict__ dout) {
  __shared__ __align__(16) short qh[64 * 64], qlo[64 * 64], kh[128 * 64], klo[128 * 64];
  __shared__ float mask_s[1024];
  __shared__ float red[4][64];
  const int t = threadIdx.x;
  const int qt = blockIdx.x, b = blockIdx.y;
  const int q0 = qt * 64;
  const int w = t >> 6, l = t & 63, wm = w >> 2, wn = w & 3, g = l >> 4, ln = l & 15;
  for (int i = t; i < 1024; i += 512) mask_s[i] = mask[b * 1024 + i];
  const f32x4 fz = {0.f, 0.f, 0.f, 0.f};
  f32x4 acc[8][2][2];
#pragma unroll
  for (int kt = 0; kt < 8; kt++)
#pragma unroll
    for (int mf = 0; mf < 2; mf++)
#pragma unroll
      for (int nf = 0; nf < 2; nf++) acc[kt][mf][nf] = fz;
  const float* qfb = dout + (size_t)(b * 1024 + q0) * 1024;
  const float* kb = Key + (size_t)b * 1024 * 1024;
  const int qrow = t >> 3, qcol = (t & 7) * 8;
  const int krow = t >> 2, kcol0 = (t & 3) * 16;
#pragma unroll 1
  for (int dc = 0; dc < 16; dc++) {
    {
      s16x8 h, lo;
      cvt8(qfb + (size_t)qrow * 1024 + dc * 64 + qcol, h, lo);
      int si = swz(qrow, qcol);
      *(s16x8*)&qh[si] = h;
      *(s16x8*)&qlo[si] = lo;
    }
#pragma unroll
    for (int kt = 0; kt < 8; kt++) {
      {
        const float* s = kb + (size_t)(kt * 128 + krow) * 1024 + dc * 64 + kcol0;
        s16x8 h, lo;
        cvt8(s, h, lo);
        int si = swz(krow, kcol0);
        *(s16x8*)&kh[si] = h;
        *(s16x8*)&klo[si] = lo;
        cvt8(s + 8, h, lo);
        si = swz(krow, kcol0 + 8);
        *(s16x8*)&kh[si] = h;
        *(s16x8*)&klo[si] = lo;
      }
      __syncthreads();
#pragma unroll
      for (int ks = 0; ks < 2; ks++) {
        const int kc = ks * 32 + g * 8;
        s16x8 ah[2], al2[2], bh[2], bl[2];
#pragma unroll
        for (int mf = 0; mf < 2; mf++) {
          int si = swz(wm * 32 + mf * 16 + ln, kc);
          ah[mf] = *(s16x8*)&qh[si];
          al2[mf] = *(s16x8*)&qlo[si];
        }
#pragma unroll
        for (int nf = 0; nf < 2; nf++) {
          int si = swz(wn * 32 + nf * 16 + ln, kc);
          bh[nf] = *(s16x8*)&kh[si];
          bl[nf] = *(s16x8*)&klo[si];
        }
#pragma unroll
        for (int mf = 0; mf < 2; mf++)
#pragma unroll
          for (int nf = 0; nf < 2; nf++) {
            acc[kt][mf][nf] = MFMA16(ah[mf], bh[nf], acc[kt][mf][nf]);
            acc[kt][mf][nf] = MFMA16(ah[mf], bl[nf], acc[kt][mf][nf]);
            acc[kt][mf][nf] = MFMA16(al2[mf], bh[nf], acc[kt][mf][nf]);
          }
      }
      __syncthreads();
    }
  }
  float rmax[2][4];
#pragma unroll
  for (int mf = 0; mf < 2; mf++)
#pragma unroll
    for (int r = 0; r < 4; r++) rmax[mf][r] = -1e30f;
#pragma unroll
  for (int kt = 0; kt < 8; kt++)
#pragma unroll
    for (int nf = 0; nf < 2; nf++) {
      const int k = kt * 128 + wn * 32 + nf * 16 + ln;
      const bool mk = mask_s[k] != 0.f;
#pragma unroll
      for (int mf = 0; mf < 2; mf++)
#pragma unroll
        for (int r = 0; r < 4; r++)
          if (mk) rmax[mf][r] = fmaxf(rmax[mf][r], acc[kt][mf][nf][r]);
    }
#pragma unroll
  for (int off = 1; off < 16; off <<= 1)
#pragma unroll
    for (int mf = 0; mf < 2; mf++)
#pragma unroll
      for (int r = 0; r < 4; r++) rmax[mf][r] = fmaxf(rmax[mf][r], __shfl_xor(rmax[mf][r], off));
  if (ln == 0) {
#pragma unroll
    for (int mf = 0; mf < 2; mf++)
#pragma unroll
      for (int r = 0; r < 4; r++) red[wn][wm * 32 + mf * 16 + g * 4 + r] = rmax[mf][r];
  }
  __syncthreads();
#pragma unroll
  for (int mf = 0; mf < 2; mf++)
#pragma unroll
    for (int r = 0; r < 4; r++) {
      const int row = wm * 32 + mf * 16 + g * 4 + r;
      rmax[mf][r] = fmaxf(fmaxf(red[0][row], red[1][row]), fmaxf(red[2][row], red[3][row]));
    }
  __syncthreads();
  float rsum[2][4];
#pragma unroll
  for (int mf = 0; mf < 2; mf++)
#pragma unroll
    for (int r = 0; r < 4; r++) rsum[mf][r] = 0.f;
#pragma unroll
  for (int kt = 0; kt < 8; kt++)
#pragma unroll
    for (int nf = 0; nf < 2; nf++) {
      const int k = kt * 128 + wn * 32 + nf * 16 + ln;
      const bool mk = mask_s[k] != 0.f;
#pragma unroll
      for (int mf = 0; mf < 2; mf++)
#pragma unroll
        for (int r = 0; r < 4; r++)
          if (mk) rsum[mf][r] += __expf(acc[kt][mf][nf][r] - rmax[mf][r]);
    }
#pragma unroll
  for (int off = 1; off < 16; off <<= 1)
#pragma unroll
    for (int mf = 0; mf < 2; mf++)
#pragma unroll
      for (int r = 0; r < 4; r++) rsum[mf][r] += __shfl_xor(rsum[mf][r], off);
  if (ln == 0) {
#pragma unroll
    for (int mf = 0; mf < 2; mf++)
#pragma unroll
      for (int r = 0; r < 4; r++) red[wn][wm * 32 + mf * 16 + g * 4 + r] = rsum[mf][r];
  }
  __syncthreads();
  float rinv[2][4];
#pragma unroll
  for (int mf = 0; mf < 2; mf++)
#pragma unroll
    for (int r = 0; r < 4; r++) {
      const int row = wm * 32 + mf * 16 + g * 4 + r;
      rinv[mf][r] = 1.f / (red[0][row] + red[1][row] + red[2][row] + red[3][row]);
    }
  char* oc = (char*)dout;
#pragma unroll
  for (int kt = 0; kt < 8; kt++)
#pragma unroll
    for (int nf = 0; nf < 2; nf++) {
      const int k = kt * 128 + wn * 32 + nf * 16 + ln;
      const bool mk = mask_s[k] != 0.f;
#pragma unroll
      for (int mf = 0; mf < 2; mf++)
#pragma unroll
        for (int r = 0; r < 4; r++) {
          const int q = q0 + wm * 32 + mf * 16 + g * 4 + r;
          float p = mk ? __expf(acc[kt][mf][nf][r] - rmax[mf][r]) * rinv[mf][r] : 0.f;
          *(unsigned short*)(oc + (size_t)(b * 1024 + q) * 4096 + 2048 + k * 2) = f2bf(p);
        }
    }
}

__global__ __launch_bounds__(512, 2) void k_pv(const float* __restrict__ Key,
                                               float* __restrict__ dout, const int dh) {
  __shared__ __align__(16) short P[128 * 64];
  __shared__ __align__(16) short KT[512 * 64];
  const int t = threadIdx.x;
  const int qt = blockIdx.x, b = blockIdx.y;
  const int q0 = qt * 128, d0 = dh * 512;
  const int w = t >> 6, l = t & 63, wm = w >> 2, wd = w & 3, g = l >> 4, ln = l & 15;
  const f32x4 fz = {0.f, 0.f, 0.f, 0.f};
  f32x4 acc[4][8];
#pragma unroll
  for (int a = 0; a < 4; a++)
#pragma unroll
    for (int bq = 0; bq < 8; bq++) acc[a][bq] = fz;
  const char* ab = (const char*)dout;
  const int prow = t >> 2, pc0 = (t & 3) * 16;
#pragma unroll 1
  for (int k0 = 0; k0 < 1024; k0 += 64) {
    {
      const unsigned short* s =
          (const unsigned short*)(ab + (size_t)(b * 1024 + q0 + prow) * 4096 + 2048) + k0 + pc0;
      s16x8 p0 = *(const s16x8*)s, p1 = *(const s16x8*)(s + 8);
      *(s16x8*)&P[swz(prow, pc0)] = p0;
      *(s16x8*)&P[swz(prow, pc0 + 8)] = p1;
    }
    {
      const float* ksrc = Key + (size_t)b * 1024 * 1024 + (size_t)k0 * 1024 + d0 + t;
#pragma unroll
      for (int kg = 0; kg < 8; kg++) {
        s16x8 h;
#pragma unroll
        for (int jx = 0; jx < 8; jx++) h[jx] = (short)f2bf(ksrc[(size_t)(kg * 8 + jx) * 1024]);
        *(s16x8*)&KT[swz(t, kg * 8)] = h;
      }
    }
    __syncthreads();
#pragma unroll
    for (int ks = 0; ks < 2; ks++) {
      const int kc = ks * 32 + g * 8;
      s16x8 a[4], bb[8];
#pragma unroll
      for (int mf = 0; mf < 4; mf++) a[mf] = *(s16x8*)&P[swz(wm * 64 + mf * 16 + ln, kc)];
#pragma unroll
      for (int nf = 0; nf < 8; nf++) bb[nf] = *(s16x8*)&KT[swz(wd * 128 + nf * 16 + ln, kc)];
#pragma unroll
      for (int mf = 0; mf < 4; mf++)
#pragma unroll
        for (int nf = 0; nf < 8; nf++) acc[mf][nf] = MFMA16(a[mf], bb[nf], acc[mf][nf]);
    }
    __syncthreads();
  }
#pragma unroll
  for (int mf = 0; mf < 4; mf++)
#pragma unroll
    for (int nf = 0; nf < 8; nf++)
#pragma unroll
      for (int r = 0; r < 4; r++) {
        const int q = q0 + wm * 64 + mf * 16 + g * 4 + r;
        const int d = d0 + wd * 128 + nf * 16 + ln;
        dout[(size_t)(b * 1024 + q) * 1024 + d] = acc[mf][nf][r];
      }
}

extern "C" void kernel_launch(void* const* d_in, const int* in_sizes, int n_in,
                              void* d_out, int out_size, void* d_ws, size_t ws_size,
                              hipStream_t stream) {
  const float* Q = (const float*)d_in[0];
  const float* K = (const float*)d_in[1];
  const float* M = (const float*)d_in[2];
  const float* W = (const float*)d_in[3];
  const float* bias = (const float*)d_in[4];
  float* out = (float*)d_out;
  char* wsb = (char*)d_ws;
  (void)in_sizes; (void)n_in; (void)out_size;

  if (ws_size >= WS_TIER_A) {
    unsigned short* Khi = (unsigned short*)(wsb + OFF_KHI);
    unsigned short* Klo = (unsigned short*)(wsb + OFF_KLO);
    unsigned short* KhiT = (unsigned short*)(wsb + OFF_KHIT);
    unsigned short* Qhi = (unsigned short*)(wsb + OFF_QHI);
    unsigned short* Qlo = (unsigned short*)(wsb + OFF_QLO);
    unsigned short* Whi = (unsigned short*)(wsb + OFF_WHI);
    unsigned short* Wlo = (unsigned short*)(wsb + OFF_WLO);
    float* Sf = (float*)(wsb + OFF_QHI);  // 128MB, Q planes dead after qf2
    unsigned short* Pw = Klo;             // dead after sgemm8
    k_cvt_qw<<<16896, 256, 0, stream>>>(Q, Qhi, Qlo, W, Whi, Wlo);
    k_qf2k<<<10240, 256, 0, stream>>>(Qhi, Qlo, Whi, Wlo, bias, out, K, Khi, Klo, KhiT);
    k_sgemm8<<<512, 512, 0, stream>>>(Khi, Klo, (const unsigned short*)out, Sf);
    k_softmax<<<32768, 256, 0, stream>>>(Sf, M, Pw);
    k_pv2<<<dim3(8, 32, 2), 512, 0, stream>>>(KhiT, Pw, out);
  } else {
    k_qf<<<dim3(256, 8), 256, 0, stream>>>(Q, W, bias, out);
    k_attn<<<dim3(16, 32), 512, 0, stream>>>(K, M, out);
    k_pv<<<dim3(8, 32), 512, 0, stream>>>(K, out, 0);
    k_pv<<<dim3(8, 32), 512, 0, stream>>>(K, out, 1);
  }
}